// Round 4
// baseline (384.174 us; speedup 1.0000x reference)
//
#include <hip/hip_runtime.h>
#include <stdint.h>

#define DIM    128
#define HEADS  8
#define INNER  1024
#define HIDDEN 512
#define BATCH  8
#define SEQ    1024
#define ROWS   8192   // BATCH*SEQ

typedef __attribute__((ext_vector_type(8))) short bf16x8;
typedef __attribute__((ext_vector_type(4))) float f32x4;
typedef __attribute__((ext_vector_type(4))) unsigned short u16x4;

static __device__ __forceinline__ float b2f(unsigned short u) {
    union { float f; unsigned int i; } v; v.i = ((unsigned int)u) << 16; return v.f;
}
static __device__ __forceinline__ unsigned short f2b(float f) {
    union { float f; unsigned int i; } v; v.f = f;
    unsigned int x = v.i;
    return (unsigned short)((x + 0x7fffu + ((x >> 16) & 1u)) >> 16);
}

// ---------------- f32 -> bf16 weight conversion ----------------
__global__ __launch_bounds__(256)
void cvt_kernel(const float* __restrict__ in, unsigned short* __restrict__ out, int n4)
{
    const int i = blockIdx.x * 256 + threadIdx.x;
    if (i < n4) {
        const float4 v = ((const float4*)in)[i];
        u16x4 o;
        o[0] = f2b(v.x); o[1] = f2b(v.y); o[2] = f2b(v.z); o[3] = f2b(v.w);
        ((u16x4*)out)[i] = o;
    }
}

// ---------------- LayerNorm: one wave per 128-elem row (f32 in, bf16 out) ----------------
__global__ __launch_bounds__(256)
void ln_kernel(const float* __restrict__ in,
               const float* __restrict__ w,
               const float* __restrict__ b,
               unsigned short* __restrict__ out, int rows)
{
    const int wave = threadIdx.x >> 6;
    const int lane = threadIdx.x & 63;
    const int row  = blockIdx.x * 4 + wave;
    if (row >= rows) return;

    const float2 xv = *(const float2*)(in + (size_t)row*DIM + lane*2);
    float x0 = xv.x, x1 = xv.y;

    float s = x0 + x1;
    float q = x0*x0 + x1*x1;
    #pragma unroll
    for (int off = 32; off > 0; off >>= 1) {
        s += __shfl_xor(s, off);
        q += __shfl_xor(q, off);
    }
    const float mu  = s * (1.0f/128.0f);
    const float var = q * (1.0f/128.0f) - mu*mu;
    const float rs  = rsqrtf(var + 1e-5f);

    const float2 wv = *(const float2*)(w + lane*2);
    const float2 bv = *(const float2*)(b + lane*2);
    unsigned short o0 = f2b((x0 - mu) * rs * wv.x + bv.x);
    unsigned short o1 = f2b((x1 - mu) * rs * wv.y + bv.y);
    *(unsigned int*)(out + (size_t)row*DIM + lane*2) = (unsigned int)o0 | ((unsigned int)o1 << 16);
}

// ---------------- Generic TN GEMM: C(MxN) = A(MxK) * W(NxK)^T ----------------
// block = 4 waves stacked in M; wave tile = 16(M) x 64(N)
// EPI: 0=q scatter, 1=kv scatter (k + v-transposed), 2=proj(+bias,*ls1,+x -> f32),
//      3=fc1(+bias,relu -> bf16), 4=fc2(+bias,*ls2,+x1 -> f32 out)
template<int K, int EPI>
__global__ __launch_bounds__(256)
void gemm_kernel(const unsigned short* __restrict__ A,
                 const unsigned short* __restrict__ W,
                 void* __restrict__ out0, void* __restrict__ out1,
                 const float* __restrict__ bias,
                 const float* __restrict__ gamma,
                 const float* __restrict__ resid)
{
    const int lane = threadIdx.x & 63;
    const int wave = threadIdx.x >> 6;
    const int g    = lane >> 4;
    const int c16  = lane & 15;
    const int mb   = blockIdx.y * 64 + wave * 16;
    const int nb   = blockIdx.x * 64;

    f32x4 acc[4];
    #pragma unroll
    for (int t = 0; t < 4; ++t) acc[t] = (f32x4){0.f, 0.f, 0.f, 0.f};

    const unsigned short* arow = A + (size_t)(mb + c16) * K;
    #pragma unroll 4
    for (int ks = 0; ks < K/32; ++ks) {
        const int koff = ks*32 + g*8;
        bf16x8 af = *(const bf16x8*)(arow + koff);
        #pragma unroll
        for (int t = 0; t < 4; ++t) {
            bf16x8 wf = *(const bf16x8*)(W + (size_t)(nb + t*16 + c16) * K + koff);
            acc[t] = __builtin_amdgcn_mfma_f32_16x16x32_bf16(af, wf, acc[t], 0, 0, 0);
        }
    }

    #pragma unroll
    for (int t = 0; t < 4; ++t) {
        #pragma unroll
        for (int r = 0; r < 4; ++r) {
            const int row = mb + g*4 + r;
            const int col = nb + t*16 + c16;
            const float v = acc[t][r];
            if (EPI == 0) {
                const int bb = row >> 10, n = row & 1023, hh = col >> 7, p = col & 127;
                ((unsigned short*)out0)[(((size_t)(bb*HEADS + hh))*SEQ + n)*DIM + p] = f2b(v);
            } else if (EPI == 1) {
                const int bb = row >> 10, m = row & 1023;
                if (col < INNER) {
                    const int hh = col >> 7, p = col & 127;
                    ((unsigned short*)out0)[(((size_t)(bb*HEADS + hh))*SEQ + m)*DIM + p] = f2b(v);
                } else {
                    const int c2 = col - INNER;
                    const int hh = c2 >> 7, p = c2 & 127;
                    ((unsigned short*)out1)[(((size_t)(bb*HEADS + hh))*DIM + p)*SEQ + m] = f2b(v);
                }
            } else if (EPI == 2) {
                const float xv = resid[(size_t)row*DIM + col];
                ((float*)out0)[(size_t)row*DIM + col] = xv + (v + bias[col]) * gamma[col];
            } else if (EPI == 3) {
                const float hv = v + bias[col];
                ((unsigned short*)out0)[(size_t)row*HIDDEN + col] = f2b(fmaxf(hv, 0.f));
            } else {
                const float ov = resid[(size_t)row*DIM + col] + (v + bias[col]) * gamma[col];
                ((float*)out0)[(size_t)row*DIM + col] = ov;
            }
        }
    }
}

// ---------------- Flash attention (swapped QK^T), 4 waves x 16 Q-rows ----------------
__global__ __launch_bounds__(256)
void attn_kernel(const unsigned short* __restrict__ qbuf,  // (B,H,N,P)
                 const unsigned short* __restrict__ kbuf,  // (B,H,M,P)
                 const unsigned short* __restrict__ vtbuf, // (B,H,P,M)
                 unsigned short* __restrict__ obuf)        // (B,N,INNER)
{
    __shared__ uint2 pls[4][2][128];   // per-wave P scratch (16 rows x 32 m bf16), dbuf

    const int lane = threadIdx.x & 63;
    const int wave = threadIdx.x >> 6;
    const int g    = lane >> 4;
    const int c16  = lane & 15;
    const int bh   = blockIdx.x >> 4;
    const int nblk = blockIdx.x & 15;
    const int n0   = nblk * 64 + wave * 16;
    const int bb   = bh >> 3, hh = bh & 7;

    const unsigned short* Q  = qbuf  + (size_t)bh * SEQ * DIM;
    const unsigned short* Kp = kbuf  + (size_t)bh * SEQ * DIM;
    const unsigned short* Vt = vtbuf + (size_t)bh * DIM * SEQ;

    bf16x8 qf[4];
    #pragma unroll
    for (int ks = 0; ks < 4; ++ks)
        qf[ks] = *(const bf16x8*)(Q + (size_t)(n0 + c16)*DIM + ks*32 + g*8);

    f32x4 oacc[8];
    #pragma unroll
    for (int pc = 0; pc < 8; ++pc) oacc[pc] = (f32x4){0.f,0.f,0.f,0.f};
    float mi = -1e30f, li = 0.f;
    const float scale = 0.08838834764831845f;  // 1/sqrt(128)

    for (int it = 0; it < 32; ++it) {
        const int mc = it * 32;
        // S^T = K_chunk * Q^T  -> lane holds S[n=c16][m = 16s + 4g + r]
        f32x4 st[2];
        #pragma unroll
        for (int s = 0; s < 2; ++s) {
            f32x4 a = (f32x4){0.f,0.f,0.f,0.f};
            #pragma unroll
            for (int ks = 0; ks < 4; ++ks) {
                bf16x8 kf = *(const bf16x8*)(Kp + (size_t)(mc + s*16 + c16)*DIM + ks*32 + g*8);
                a = __builtin_amdgcn_mfma_f32_16x16x32_bf16(kf, qf[ks], a, 0, 0, 0);
            }
            st[s] = a;
        }
        float cmax = -1e30f;
        #pragma unroll
        for (int s = 0; s < 2; ++s)
            #pragma unroll
            for (int r = 0; r < 4; ++r) { st[s][r] *= scale; cmax = fmaxf(cmax, st[s][r]); }
        cmax = fmaxf(cmax, __shfl_xor(cmax, 16));
        cmax = fmaxf(cmax, __shfl_xor(cmax, 32));
        const float mnew  = fmaxf(mi, cmax);
        const float alpha = __expf(mi - mnew);

        float psum = 0.f;
        uint2 pw[2];
        #pragma unroll
        for (int s = 0; s < 2; ++s) {
            float p0 = __expf(st[s][0] - mnew), p1 = __expf(st[s][1] - mnew);
            float p2 = __expf(st[s][2] - mnew), p3 = __expf(st[s][3] - mnew);
            psum += (p0 + p1) + (p2 + p3);
            pw[s].x = (unsigned int)f2b(p0) | ((unsigned int)f2b(p1) << 16);
            pw[s].y = (unsigned int)f2b(p2) | ((unsigned int)f2b(p3) << 16);
        }
        psum += __shfl_xor(psum, 16);
        psum += __shfl_xor(psum, 32);
        li = li * alpha + psum;
        mi = mnew;

        const int db = it & 1;
        pls[wave][db][c16*8 + 0*4 + g] = pw[0];
        pls[wave][db][c16*8 + 1*4 + g] = pw[1];

        // rescale o accumulator (rows n = 4g + r; stats live at lane index n)
        float ar[4];
        #pragma unroll
        for (int r = 0; r < 4; ++r) ar[r] = __shfl(alpha, g*4 + r);
        #pragma unroll
        for (int pc = 0; pc < 8; ++pc)
            #pragma unroll
            for (int r = 0; r < 4; ++r) oacc[pc][r] *= ar[r];

        // per-wave LDS scratch: in-wave ds_write->ds_read ordering handled by compiler
        const unsigned short* pbase = (const unsigned short*)&pls[wave][db][0];
        bf16x8 pa = *(const bf16x8*)(pbase + c16*32 + g*8);
        #pragma unroll
        for (int pc = 0; pc < 8; ++pc) {
            bf16x8 vf = *(const bf16x8*)(Vt + (size_t)(pc*16 + c16)*SEQ + mc + g*8);
            oacc[pc] = __builtin_amdgcn_mfma_f32_16x16x32_bf16(pa, vf, oacc[pc], 0, 0, 0);
        }
    }

    float lr[4];
    #pragma unroll
    for (int r = 0; r < 4; ++r) lr[r] = 1.f / __shfl(li, g*4 + r);
    #pragma unroll
    for (int pc = 0; pc < 8; ++pc)
        #pragma unroll
        for (int r = 0; r < 4; ++r) {
            const int n = n0 + g*4 + r;
            obuf[((size_t)bb*SEQ + n)*INNER + hh*DIM + pc*16 + c16] = f2b(oacc[pc][r] * lr[r]);
        }
}

// ---------------- launch ----------------
extern "C" void kernel_launch(void* const* d_in, const int* in_sizes, int n_in,
                              void* d_out, int out_size, void* d_ws, size_t ws_size,
                              hipStream_t stream)
{
    const float* x         = (const float*)d_in[0];
    const float* y         = (const float*)d_in[1];
    const float* norm_x_w  = (const float*)d_in[2];
    const float* norm_x_b  = (const float*)d_in[3];
    const float* norm_y_w  = (const float*)d_in[4];
    const float* norm_y_b  = (const float*)d_in[5];
    const float* q_w       = (const float*)d_in[6];
    const float* kv_w      = (const float*)d_in[7];
    const float* proj_w    = (const float*)d_in[8];
    const float* proj_b    = (const float*)d_in[9];
    const float* ls1_gamma = (const float*)d_in[10];
    const float* norm_o_w  = (const float*)d_in[11];
    const float* norm_o_b  = (const float*)d_in[12];
    const float* fc1_w     = (const float*)d_in[13];
    const float* fc1_b     = (const float*)d_in[14];
    const float* fc2_w     = (const float*)d_in[15];
    const float* fc2_b     = (const float*)d_in[16];
    const float* ls2_gamma = (const float*)d_in[17];

    char* ws = (char*)d_ws;
    size_t off = 0;
    auto alloc = [&](size_t bytes) {
        void* p = ws + off;
        off += (bytes + 255) & ~(size_t)255;
        return p;
    };
    unsigned short* xn  = (unsigned short*)alloc((size_t)ROWS*DIM*2);
    unsigned short* yn  = (unsigned short*)alloc((size_t)ROWS*DIM*2);
    unsigned short* qb  = (unsigned short*)alloc((size_t)ROWS*INNER*2);
    unsigned short* kb  = (unsigned short*)alloc((size_t)ROWS*INNER*2);
    unsigned short* vtb = (unsigned short*)alloc((size_t)ROWS*INNER*2);
    unsigned short* ob  = (unsigned short*)alloc((size_t)ROWS*INNER*2);
    float*          x1  = (float*)alloc((size_t)ROWS*DIM*4);
    unsigned short* hin = (unsigned short*)alloc((size_t)ROWS*DIM*2);
    unsigned short* h1  = (unsigned short*)alloc((size_t)ROWS*HIDDEN*2);
    unsigned short* wq   = (unsigned short*)alloc((size_t)INNER*DIM*2);
    unsigned short* wkv  = (unsigned short*)alloc((size_t)2*INNER*DIM*2);
    unsigned short* wpr  = (unsigned short*)alloc((size_t)DIM*INNER*2);
    unsigned short* wf1  = (unsigned short*)alloc((size_t)HIDDEN*DIM*2);
    unsigned short* wf2  = (unsigned short*)alloc((size_t)DIM*HIDDEN*2);

    // 0) convert weights f32 -> bf16
    cvt_kernel<<<dim3(INNER*DIM/1024),    256, 0, stream>>>(q_w,    wq,  INNER*DIM/4);
    cvt_kernel<<<dim3(2*INNER*DIM/1024),  256, 0, stream>>>(kv_w,   wkv, 2*INNER*DIM/4);
    cvt_kernel<<<dim3(DIM*INNER/1024),    256, 0, stream>>>(proj_w, wpr, DIM*INNER/4);
    cvt_kernel<<<dim3(HIDDEN*DIM/1024),   256, 0, stream>>>(fc1_w,  wf1, HIDDEN*DIM/4);
    cvt_kernel<<<dim3(DIM*HIDDEN/1024),   256, 0, stream>>>(fc2_w,  wf2, DIM*HIDDEN/4);

    // 1) LayerNorms of x and y  (f32 in -> bf16 out)
    ln_kernel<<<dim3(ROWS/4), 256, 0, stream>>>(x, norm_x_w, norm_x_b, xn, ROWS);
    ln_kernel<<<dim3(ROWS/4), 256, 0, stream>>>(y, norm_y_w, norm_y_b, yn, ROWS);

    // 2) q / kv projections
    gemm_kernel<128, 0><<<dim3(INNER/64, ROWS/64), 256, 0, stream>>>(
        xn, wq, qb, nullptr, nullptr, nullptr, nullptr);
    gemm_kernel<128, 1><<<dim3(2*INNER/64, ROWS/64), 256, 0, stream>>>(
        yn, wkv, kb, vtb, nullptr, nullptr, nullptr);

    // 3) attention
    attn_kernel<<<dim3(BATCH*HEADS*16), 256, 0, stream>>>(qb, kb, vtb, ob);

    // 4) proj + bias + ls1*resid(x,f32) -> x1 (f32)
    gemm_kernel<1024, 2><<<dim3(DIM/64, ROWS/64), 256, 0, stream>>>(
        ob, wpr, x1, nullptr, proj_b, ls1_gamma, x);

    // 5) LN(x1) -> hin (bf16)
    ln_kernel<<<dim3(ROWS/4), 256, 0, stream>>>(x1, norm_o_w, norm_o_b, hin, ROWS);

    // 6) fc1 + relu -> h1 (bf16)
    gemm_kernel<128, 3><<<dim3(HIDDEN/64, ROWS/64), 256, 0, stream>>>(
        hin, wf1, h1, nullptr, fc1_b, nullptr, nullptr);

    // 7) fc2 + bias + ls2*resid(x1,f32) -> d_out (f32)
    gemm_kernel<512, 4><<<dim3(DIM/64, ROWS/64), 256, 0, stream>>>(
        h1, wf2, d_out, nullptr, fc2_b, ls2_gamma, x1);
}

// Round 5
// 384.010 us; speedup vs baseline: 1.0004x; 1.0004x over previous
//
#include <hip/hip_runtime.h>
#include <stdint.h>

#define DIM    128
#define HEADS  8
#define INNER  1024
#define HIDDEN 512
#define BATCH  8
#define SEQ    1024
#define ROWS   8192   // BATCH*SEQ

typedef __attribute__((ext_vector_type(8))) short bf16x8;
typedef __attribute__((ext_vector_type(4))) float f32x4;
typedef __attribute__((ext_vector_type(4))) unsigned short u16x4;

static __device__ __forceinline__ float b2f(unsigned short u) {
    union { float f; unsigned int i; } v; v.i = ((unsigned int)u) << 16; return v.f;
}
static __device__ __forceinline__ unsigned short f2b(float f) {
    union { float f; unsigned int i; } v; v.f = f;
    unsigned int x = v.i;
    return (unsigned short)((x + 0x7fffu + ((x >> 16) & 1u)) >> 16);
}

// ---------------- f32 -> bf16 weight conversion ----------------
__global__ __launch_bounds__(256)
void cvt_kernel(const float* __restrict__ in, unsigned short* __restrict__ out, int n4)
{
    const int i = blockIdx.x * 256 + threadIdx.x;
    if (i < n4) {
        const float4 v = ((const float4*)in)[i];
        u16x4 o;
        o[0] = f2b(v.x); o[1] = f2b(v.y); o[2] = f2b(v.z); o[3] = f2b(v.w);
        ((u16x4*)out)[i] = o;
    }
}

// ---------------- LayerNorm: one wave per 128-elem row (f32 in, bf16 out) ----------------
__global__ __launch_bounds__(256)
void ln_kernel(const float* __restrict__ in,
               const float* __restrict__ w,
               const float* __restrict__ b,
               unsigned short* __restrict__ out, int rows)
{
    const int wave = threadIdx.x >> 6;
    const int lane = threadIdx.x & 63;
    const int row  = blockIdx.x * 4 + wave;
    if (row >= rows) return;

    const float2 xv = *(const float2*)(in + (size_t)row*DIM + lane*2);
    float x0 = xv.x, x1 = xv.y;

    float s = x0 + x1;
    float q = x0*x0 + x1*x1;
    #pragma unroll
    for (int off = 32; off > 0; off >>= 1) {
        s += __shfl_xor(s, off);
        q += __shfl_xor(q, off);
    }
    const float mu  = s * (1.0f/128.0f);
    const float var = q * (1.0f/128.0f) - mu*mu;
    const float rs  = rsqrtf(var + 1e-5f);

    const float2 wv = *(const float2*)(w + lane*2);
    const float2 bv = *(const float2*)(b + lane*2);
    unsigned short o0 = f2b((x0 - mu) * rs * wv.x + bv.x);
    unsigned short o1 = f2b((x1 - mu) * rs * wv.y + bv.y);
    *(unsigned int*)(out + (size_t)row*DIM + lane*2) = (unsigned int)o0 | ((unsigned int)o1 << 16);
}

// ---------------- Generic TN GEMM: C(MxN) = A(MxK) * W(NxK)^T ----------------
// block = 4 waves stacked in M; wave tile = 16(M) x 64(N)
// EPI: 0=q scatter, 1=kv scatter (k + v-transposed), 2=proj(+bias,*ls1,+x -> f32),
//      3=fc1(+bias,relu -> bf16), 4=fc2(+bias,*ls2,+x1 -> f32 out)
template<int K, int EPI>
__global__ __launch_bounds__(256)
void gemm_kernel(const unsigned short* __restrict__ A,
                 const unsigned short* __restrict__ W,
                 void* __restrict__ out0, void* __restrict__ out1,
                 const float* __restrict__ bias,
                 const float* __restrict__ gamma,
                 const float* __restrict__ resid)
{
    const int lane = threadIdx.x & 63;
    const int wave = threadIdx.x >> 6;
    const int g    = lane >> 4;
    const int c16  = lane & 15;
    const int mb   = blockIdx.y * 64 + wave * 16;
    const int nb   = blockIdx.x * 64;

    f32x4 acc[4];
    #pragma unroll
    for (int t = 0; t < 4; ++t) acc[t] = (f32x4){0.f, 0.f, 0.f, 0.f};

    const unsigned short* arow = A + (size_t)(mb + c16) * K;
    #pragma unroll 4
    for (int ks = 0; ks < K/32; ++ks) {
        const int koff = ks*32 + g*8;
        bf16x8 af = *(const bf16x8*)(arow + koff);
        #pragma unroll
        for (int t = 0; t < 4; ++t) {
            bf16x8 wf = *(const bf16x8*)(W + (size_t)(nb + t*16 + c16) * K + koff);
            acc[t] = __builtin_amdgcn_mfma_f32_16x16x32_bf16(af, wf, acc[t], 0, 0, 0);
        }
    }

    #pragma unroll
    for (int t = 0; t < 4; ++t) {
        #pragma unroll
        for (int r = 0; r < 4; ++r) {
            const int row = mb + g*4 + r;
            const int col = nb + t*16 + c16;
            const float v = acc[t][r];
            if (EPI == 0) {
                const int bb = row >> 10, n = row & 1023, hh = col >> 7, p = col & 127;
                ((unsigned short*)out0)[(((size_t)(bb*HEADS + hh))*SEQ + n)*DIM + p] = f2b(v);
            } else if (EPI == 1) {
                const int bb = row >> 10, m = row & 1023;
                if (col < INNER) {
                    const int hh = col >> 7, p = col & 127;
                    ((unsigned short*)out0)[(((size_t)(bb*HEADS + hh))*SEQ + m)*DIM + p] = f2b(v);
                } else {
                    const int c2 = col - INNER;
                    const int hh = c2 >> 7, p = c2 & 127;
                    ((unsigned short*)out1)[(((size_t)(bb*HEADS + hh))*DIM + p)*SEQ + m] = f2b(v);
                }
            } else if (EPI == 2) {
                const float xv = resid[(size_t)row*DIM + col];
                ((float*)out0)[(size_t)row*DIM + col] = xv + (v + bias[col]) * gamma[col];
            } else if (EPI == 3) {
                const float hv = v + bias[col];
                ((unsigned short*)out0)[(size_t)row*HIDDEN + col] = f2b(fmaxf(hv, 0.f));
            } else {
                const float ov = resid[(size_t)row*DIM + col] + (v + bias[col]) * gamma[col];
                ((float*)out0)[(size_t)row*DIM + col] = ov;
            }
        }
    }
}

// ---------------- Flash attention (swapped QK^T), 4 waves x 16 Q-rows ----------------
__global__ __launch_bounds__(256)
void attn_kernel(const unsigned short* __restrict__ qbuf,  // (B,H,N,P)
                 const unsigned short* __restrict__ kbuf,  // (B,H,M,P)
                 const unsigned short* __restrict__ vtbuf, // (B,H,P,M)
                 unsigned short* __restrict__ obuf)        // (B,N,INNER)
{
    __shared__ uint2 pls[4][2][128];   // per-wave P scratch (16 rows x 32 m bf16), dbuf

    const int lane = threadIdx.x & 63;
    const int wave = threadIdx.x >> 6;
    const int g    = lane >> 4;
    const int c16  = lane & 15;
    const int bh   = blockIdx.x >> 4;
    const int nblk = blockIdx.x & 15;
    const int n0   = nblk * 64 + wave * 16;
    const int bb   = bh >> 3, hh = bh & 7;

    const unsigned short* Q  = qbuf  + (size_t)bh * SEQ * DIM;
    const unsigned short* Kp = kbuf  + (size_t)bh * SEQ * DIM;
    const unsigned short* Vt = vtbuf + (size_t)bh * DIM * SEQ;

    bf16x8 qf[4];
    #pragma unroll
    for (int ks = 0; ks < 4; ++ks)
        qf[ks] = *(const bf16x8*)(Q + (size_t)(n0 + c16)*DIM + ks*32 + g*8);

    f32x4 oacc[8];
    #pragma unroll
    for (int pc = 0; pc < 8; ++pc) oacc[pc] = (f32x4){0.f,0.f,0.f,0.f};
    float mi = -1e30f, li = 0.f;
    const float scale = 0.08838834764831845f;  // 1/sqrt(128)

    for (int it = 0; it < 32; ++it) {
        const int mc = it * 32;
        // S^T = K_chunk * Q^T  -> lane holds S[n=c16][m = 16s + 4g + r]
        f32x4 st[2];
        #pragma unroll
        for (int s = 0; s < 2; ++s) {
            f32x4 a = (f32x4){0.f,0.f,0.f,0.f};
            #pragma unroll
            for (int ks = 0; ks < 4; ++ks) {
                bf16x8 kf = *(const bf16x8*)(Kp + (size_t)(mc + s*16 + c16)*DIM + ks*32 + g*8);
                a = __builtin_amdgcn_mfma_f32_16x16x32_bf16(kf, qf[ks], a, 0, 0, 0);
            }
            st[s] = a;
        }
        float cmax = -1e30f;
        #pragma unroll
        for (int s = 0; s < 2; ++s)
            #pragma unroll
            for (int r = 0; r < 4; ++r) { st[s][r] *= scale; cmax = fmaxf(cmax, st[s][r]); }
        cmax = fmaxf(cmax, __shfl_xor(cmax, 16));
        cmax = fmaxf(cmax, __shfl_xor(cmax, 32));
        const float mnew  = fmaxf(mi, cmax);
        const float alpha = __expf(mi - mnew);

        float psum = 0.f;
        uint2 pw[2];
        #pragma unroll
        for (int s = 0; s < 2; ++s) {
            float p0 = __expf(st[s][0] - mnew), p1 = __expf(st[s][1] - mnew);
            float p2 = __expf(st[s][2] - mnew), p3 = __expf(st[s][3] - mnew);
            psum += (p0 + p1) + (p2 + p3);
            pw[s].x = (unsigned int)f2b(p0) | ((unsigned int)f2b(p1) << 16);
            pw[s].y = (unsigned int)f2b(p2) | ((unsigned int)f2b(p3) << 16);
        }
        psum += __shfl_xor(psum, 16);
        psum += __shfl_xor(psum, 32);
        li = li * alpha + psum;
        mi = mnew;

        const int db = it & 1;
        pls[wave][db][c16*8 + 0*4 + g] = pw[0];
        pls[wave][db][c16*8 + 1*4 + g] = pw[1];

        // rescale o accumulator (rows n = 4g + r; stats live at lane index n)
        float ar[4];
        #pragma unroll
        for (int r = 0; r < 4; ++r) ar[r] = __shfl(alpha, g*4 + r);
        #pragma unroll
        for (int pc = 0; pc < 8; ++pc)
            #pragma unroll
            for (int r = 0; r < 4; ++r) oacc[pc][r] *= ar[r];

        // per-wave LDS scratch: in-wave ds_write->ds_read ordering handled by compiler
        const unsigned short* pbase = (const unsigned short*)&pls[wave][db][0];
        bf16x8 pa = *(const bf16x8*)(pbase + c16*32 + g*8);
        #pragma unroll
        for (int pc = 0; pc < 8; ++pc) {
            bf16x8 vf = *(const bf16x8*)(Vt + (size_t)(pc*16 + c16)*SEQ + mc + g*8);
            oacc[pc] = __builtin_amdgcn_mfma_f32_16x16x32_bf16(pa, vf, oacc[pc], 0, 0, 0);
        }
    }

    float lr[4];
    #pragma unroll
    for (int r = 0; r < 4; ++r) lr[r] = 1.f / __shfl(li, g*4 + r);
    #pragma unroll
    for (int pc = 0; pc < 8; ++pc)
        #pragma unroll
        for (int r = 0; r < 4; ++r) {
            const int n = n0 + g*4 + r;
            obuf[((size_t)bb*SEQ + n)*INNER + hh*DIM + pc*16 + c16] = f2b(oacc[pc][r] * lr[r]);
        }
}

// ---------------- launch ----------------
extern "C" void kernel_launch(void* const* d_in, const int* in_sizes, int n_in,
                              void* d_out, int out_size, void* d_ws, size_t ws_size,
                              hipStream_t stream)
{
    const float* x         = (const float*)d_in[0];
    const float* y         = (const float*)d_in[1];
    const float* norm_x_w  = (const float*)d_in[2];
    const float* norm_x_b  = (const float*)d_in[3];
    const float* norm_y_w  = (const float*)d_in[4];
    const float* norm_y_b  = (const float*)d_in[5];
    const float* q_w       = (const float*)d_in[6];
    const float* kv_w      = (const float*)d_in[7];
    const float* proj_w    = (const float*)d_in[8];
    const float* proj_b    = (const float*)d_in[9];
    const float* ls1_gamma = (const float*)d_in[10];
    const float* norm_o_w  = (const float*)d_in[11];
    const float* norm_o_b  = (const float*)d_in[12];
    const float* fc1_w     = (const float*)d_in[13];
    const float* fc1_b     = (const float*)d_in[14];
    const float* fc2_w     = (const float*)d_in[15];
    const float* fc2_b     = (const float*)d_in[16];
    const float* ls2_gamma = (const float*)d_in[17];

    char* ws = (char*)d_ws;
    size_t off = 0;
    auto alloc = [&](size_t bytes) {
        void* p = ws + off;
        off += (bytes + 255) & ~(size_t)255;
        return p;
    };
    unsigned short* xn  = (unsigned short*)alloc((size_t)ROWS*DIM*2);
    unsigned short* yn  = (unsigned short*)alloc((size_t)ROWS*DIM*2);
    unsigned short* qb  = (unsigned short*)alloc((size_t)ROWS*INNER*2);
    unsigned short* kb  = (unsigned short*)alloc((size_t)ROWS*INNER*2);
    unsigned short* vtb = (unsigned short*)alloc((size_t)ROWS*INNER*2);
    unsigned short* ob  = (unsigned short*)alloc((size_t)ROWS*INNER*2);
    float*          x1  = (float*)alloc((size_t)ROWS*DIM*4);
    unsigned short* hin = (unsigned short*)alloc((size_t)ROWS*DIM*2);
    unsigned short* h1  = (unsigned short*)alloc((size_t)ROWS*HIDDEN*2);
    unsigned short* wq   = (unsigned short*)alloc((size_t)INNER*DIM*2);
    unsigned short* wkv  = (unsigned short*)alloc((size_t)2*INNER*DIM*2);
    unsigned short* wpr  = (unsigned short*)alloc((size_t)DIM*INNER*2);
    unsigned short* wf1  = (unsigned short*)alloc((size_t)HIDDEN*DIM*2);
    unsigned short* wf2  = (unsigned short*)alloc((size_t)DIM*HIDDEN*2);

    // 0) convert weights f32 -> bf16
    cvt_kernel<<<dim3(INNER*DIM/1024),    256, 0, stream>>>(q_w,    wq,  INNER*DIM/4);
    cvt_kernel<<<dim3(2*INNER*DIM/1024),  256, 0, stream>>>(kv_w,   wkv, 2*INNER*DIM/4);
    cvt_kernel<<<dim3(DIM*INNER/1024),    256, 0, stream>>>(proj_w, wpr, DIM*INNER/4);
    cvt_kernel<<<dim3(HIDDEN*DIM/1024),   256, 0, stream>>>(fc1_w,  wf1, HIDDEN*DIM/4);
    cvt_kernel<<<dim3(DIM*HIDDEN/1024),   256, 0, stream>>>(fc2_w,  wf2, DIM*HIDDEN/4);

    // 1) LayerNorms of x and y  (f32 in -> bf16 out)
    ln_kernel<<<dim3(ROWS/4), 256, 0, stream>>>(x, norm_x_w, norm_x_b, xn, ROWS);
    ln_kernel<<<dim3(ROWS/4), 256, 0, stream>>>(y, norm_y_w, norm_y_b, yn, ROWS);

    // 2) q / kv projections
    gemm_kernel<128, 0><<<dim3(INNER/64, ROWS/64), 256, 0, stream>>>(
        xn, wq, qb, nullptr, nullptr, nullptr, nullptr);
    gemm_kernel<128, 1><<<dim3(2*INNER/64, ROWS/64), 256, 0, stream>>>(
        yn, wkv, kb, vtb, nullptr, nullptr, nullptr);

    // 3) attention
    attn_kernel<<<dim3(BATCH*HEADS*16), 256, 0, stream>>>(qb, kb, vtb, ob);

    // 4) proj + bias + ls1*resid(x,f32) -> x1 (f32)
    gemm_kernel<1024, 2><<<dim3(DIM/64, ROWS/64), 256, 0, stream>>>(
        ob, wpr, x1, nullptr, proj_b, ls1_gamma, x);

    // 5) LN(x1) -> hin (bf16)
    ln_kernel<<<dim3(ROWS/4), 256, 0, stream>>>(x1, norm_o_w, norm_o_b, hin, ROWS);

    // 6) fc1 + relu -> h1 (bf16)
    gemm_kernel<128, 3><<<dim3(HIDDEN/64, ROWS/64), 256, 0, stream>>>(
        hin, wf1, h1, nullptr, fc1_b, nullptr, nullptr);

    // 7) fc2 + bias + ls2*resid(x1,f32) -> d_out (f32)
    gemm_kernel<512, 4><<<dim3(DIM/64, ROWS/64), 256, 0, stream>>>(
        h1, wf2, d_out, nullptr, fc2_b, ls2_gamma, x1);
}

// Round 6
// 248.600 us; speedup vs baseline: 1.5454x; 1.5447x over previous
//
#include <hip/hip_runtime.h>
#include <stdint.h>

#define DIM    128
#define HEADS  8
#define INNER  1024
#define HIDDEN 512
#define BATCH  8
#define SEQ    1024
#define ROWS   8192   // BATCH*SEQ

typedef __attribute__((ext_vector_type(8))) short bf16x8;
typedef __attribute__((ext_vector_type(4))) float f32x4;
typedef __attribute__((ext_vector_type(4))) unsigned short u16x4;

static __device__ __forceinline__ float b2f(unsigned short u) {
    union { float f; unsigned int i; } v; v.i = ((unsigned int)u) << 16; return v.f;
}
static __device__ __forceinline__ unsigned short f2b(float f) {
    union { float f; unsigned int i; } v; v.f = f;
    unsigned int x = v.i;
    return (unsigned short)((x + 0x7fffu + ((x >> 16) & 1u)) >> 16);
}

// ---------------- all weight conversions f32 -> bf16 in one launch ----------------
// segments (float4 units): q_w 32768 | kv_w 65536 | proj_w 32768 | fc1_w 16384 | fc2_w 16384
__global__ __launch_bounds__(256)
void cvt_all_kernel(const float* __restrict__ s0, unsigned short* __restrict__ d0,
                    const float* __restrict__ s1, unsigned short* __restrict__ d1,
                    const float* __restrict__ s2, unsigned short* __restrict__ d2,
                    const float* __restrict__ s3, unsigned short* __restrict__ d3,
                    const float* __restrict__ s4, unsigned short* __restrict__ d4)
{
    int j = blockIdx.x * 256 + threadIdx.x;
    const float* s; unsigned short* d;
    if (j < 32768)                 { s = s0; d = d0; }
    else if ((j -= 32768) < 65536) { s = s1; d = d1; }
    else if ((j -= 65536) < 32768) { s = s2; d = d2; }
    else if ((j -= 32768) < 16384) { s = s3; d = d3; }
    else { j -= 16384;               s = s4; d = d4; }
    const float4 v = ((const float4*)s)[j];
    u16x4 o;
    o[0] = f2b(v.x); o[1] = f2b(v.y); o[2] = f2b(v.z); o[3] = f2b(v.w);
    ((u16x4*)d)[j] = o;
}

// ---------------- LayerNorm core ----------------
static __device__ __forceinline__ void ln_row(const float* __restrict__ in,
                                              const float* __restrict__ w,
                                              const float* __restrict__ b,
                                              unsigned short* __restrict__ out,
                                              int row, int lane)
{
    const float2 xv = *(const float2*)(in + (size_t)row*DIM + lane*2);
    float x0 = xv.x, x1 = xv.y;
    float s = x0 + x1;
    float q = x0*x0 + x1*x1;
    #pragma unroll
    for (int off = 32; off > 0; off >>= 1) {
        s += __shfl_xor(s, off);
        q += __shfl_xor(q, off);
    }
    const float mu  = s * (1.0f/128.0f);
    const float var = q * (1.0f/128.0f) - mu*mu;
    const float rs  = rsqrtf(var + 1e-5f);
    const float2 wv = *(const float2*)(w + lane*2);
    const float2 bv = *(const float2*)(b + lane*2);
    unsigned short o0 = f2b((x0 - mu) * rs * wv.x + bv.x);
    unsigned short o1 = f2b((x1 - mu) * rs * wv.y + bv.y);
    *(unsigned int*)(out + (size_t)row*DIM + lane*2) = (unsigned int)o0 | ((unsigned int)o1 << 16);
}

__global__ __launch_bounds__(256)
void ln_kernel(const float* __restrict__ in,
               const float* __restrict__ w,
               const float* __restrict__ b,
               unsigned short* __restrict__ out)
{
    const int wave = threadIdx.x >> 6;
    const int lane = threadIdx.x & 63;
    ln_row(in, w, b, out, blockIdx.x * 4 + wave, lane);
}

// dual LN: blockIdx.y = 0 -> (x), 1 -> (y)
__global__ __launch_bounds__(256)
void ln_dual_kernel(const float* __restrict__ inx, const float* __restrict__ wx,
                    const float* __restrict__ bx, unsigned short* __restrict__ outx,
                    const float* __restrict__ iny, const float* __restrict__ wy,
                    const float* __restrict__ by, unsigned short* __restrict__ outy)
{
    const int wave = threadIdx.x >> 6;
    const int lane = threadIdx.x & 63;
    const int row  = blockIdx.x * 4 + wave;
    if (blockIdx.y == 0) ln_row(inx, wx, bx, outx, row, lane);
    else                 ln_row(iny, wy, by, outy, row, lane);
}

// ---------------- Generic TN GEMM: C(MxN) = A(MxK) * W(NxK)^T ----------------
// block = 4 waves stacked in M; wave tile = 16(M) x 64(N)
// EPI: 0=q scatter, 1=kv scatter into attention-permuted K/V layouts,
//      2=proj(+bias,*ls1,+x -> f32), 3=fc1(+bias,relu -> bf16), 4=fc2(+bias,*ls2,+x1 -> f32 out)
template<int K, int EPI>
__global__ __launch_bounds__(256)
void gemm_kernel(const unsigned short* __restrict__ A,
                 const unsigned short* __restrict__ W,
                 void* __restrict__ out0, void* __restrict__ out1,
                 const float* __restrict__ bias,
                 const float* __restrict__ gamma,
                 const float* __restrict__ resid)
{
    const int lane = threadIdx.x & 63;
    const int wave = threadIdx.x >> 6;
    const int g    = lane >> 4;
    const int c16  = lane & 15;
    const int mb   = blockIdx.y * 64 + wave * 16;
    const int nb   = blockIdx.x * 64;

    f32x4 acc[4];
    #pragma unroll
    for (int t = 0; t < 4; ++t) acc[t] = (f32x4){0.f, 0.f, 0.f, 0.f};

    const unsigned short* arow = A + (size_t)(mb + c16) * K;
    #pragma unroll 4
    for (int ks = 0; ks < K/32; ++ks) {
        const int koff = ks*32 + g*8;
        bf16x8 af = *(const bf16x8*)(arow + koff);
        #pragma unroll
        for (int t = 0; t < 4; ++t) {
            bf16x8 wf = *(const bf16x8*)(W + (size_t)(nb + t*16 + c16) * K + koff);
            acc[t] = __builtin_amdgcn_mfma_f32_16x16x32_bf16(af, wf, acc[t], 0, 0, 0);
        }
    }

    #pragma unroll
    for (int t = 0; t < 4; ++t) {
        #pragma unroll
        for (int r = 0; r < 4; ++r) {
            const int row = mb + g*4 + r;
            const int col = nb + t*16 + c16;
            const float v = acc[t][r];
            if (EPI == 0) {
                const int bb = row >> 10, n = row & 1023, hh = col >> 7, p = col & 127;
                ((unsigned short*)out0)[(((size_t)(bb*HEADS + hh))*SEQ + n)*DIM + p] = f2b(v);
            } else if (EPI == 1) {
                const int bb = row >> 10, m = row & 1023;
                const int chunk = m >> 5;
                if (col < INNER) {
                    // K permuted: [chunk][s:2][ks:4][g:4][c16:16][e:8]
                    const int hh = col >> 7, p = col & 127;
                    const int sl = (m >> 4) & 1, cl = m & 15;
                    const int ksl = p >> 5, gl = (p >> 3) & 3, el = p & 7;
                    ((unsigned short*)out0)[(size_t)(bb*HEADS + hh)*SEQ*DIM
                        + (size_t)((chunk*8 + sl*4 + ksl)*64 + gl*16 + cl)*8 + el] = f2b(v);
                } else {
                    // V permuted: [chunk][pc:8][c16:16][g:4][e:8]
                    const int c2 = col - INNER;
                    const int hh = c2 >> 7, p = c2 & 127;
                    const int gl = (m >> 3) & 3, el = m & 7;
                    const int pcl = p >> 4, cl = p & 15;
                    ((unsigned short*)out1)[(size_t)(bb*HEADS + hh)*SEQ*DIM
                        + (size_t)((chunk*8 + pcl)*64 + cl*4 + gl)*8 + el] = f2b(v);
                }
            } else if (EPI == 2) {
                const float xv = resid[(size_t)row*DIM + col];
                ((float*)out0)[(size_t)row*DIM + col] = xv + (v + bias[col]) * gamma[col];
            } else if (EPI == 3) {
                const float hv = v + bias[col];
                ((unsigned short*)out0)[(size_t)row*HIDDEN + col] = f2b(fmaxf(hv, 0.f));
            } else {
                const float ov = resid[(size_t)row*DIM + col] + (v + bias[col]) * gamma[col];
                ((float*)out0)[(size_t)row*DIM + col] = ov;
            }
        }
    }
}

// ---------------- Flash attention (swapped QK^T), 4 waves x 16 Q-rows ----------------
// K/V come pre-permuted so every fragment load is a fully-coalesced 1KB wave load.
__global__ __launch_bounds__(256, 4)
void attn_kernel(const unsigned short* __restrict__ qbuf,  // (B,H,N,P) plain
                 const unsigned short* __restrict__ kperm, // per bh: [chunk][s][ks][lane][8]
                 const unsigned short* __restrict__ vperm, // per bh: [chunk][pc][c16][g][8]
                 unsigned short* __restrict__ obuf)        // (B,N,INNER)
{
    // P scratch: padded row stride 40 ushorts (80B) -> near-minimal bank multiplicity
    __shared__ unsigned short pls[4][2][16*40];

    const int lane = threadIdx.x & 63;
    const int wave = threadIdx.x >> 6;
    const int g    = lane >> 4;
    const int c16  = lane & 15;
    const int bh   = blockIdx.x >> 4;
    const int nblk = blockIdx.x & 15;
    const int n0   = nblk * 64 + wave * 16;
    const int bb   = bh >> 3, hh = bh & 7;

    const unsigned short* Q  = qbuf  + (size_t)bh * SEQ * DIM;
    const unsigned short* Kb = kperm + (size_t)bh * SEQ * DIM;
    const unsigned short* Vb = vperm + (size_t)bh * SEQ * DIM;

    bf16x8 qf[4];
    #pragma unroll
    for (int ks = 0; ks < 4; ++ks)
        qf[ks] = *(const bf16x8*)(Q + (size_t)(n0 + c16)*DIM + ks*32 + g*8);

    f32x4 oacc[8];
    #pragma unroll
    for (int pc = 0; pc < 8; ++pc) oacc[pc] = (f32x4){0.f,0.f,0.f,0.f};
    float mi = -1e30f, li = 0.f;
    const float scale = 0.08838834764831845f;  // 1/sqrt(128)

    // preload K fragments for chunk 0 (coalesced: 64 lanes x 16B contiguous)
    bf16x8 kf[2][4];
    #pragma unroll
    for (int s = 0; s < 2; ++s)
        #pragma unroll
        for (int ks = 0; ks < 4; ++ks)
            kf[s][ks] = *(const bf16x8*)(Kb + (size_t)((s*4 + ks)*64 + lane)*8);

    for (int it = 0; it < 32; ++it) {
        const size_t cbase = (size_t)it * 4096;

        // issue all V loads for this chunk up front (independent of QK^T)
        bf16x8 vf[8];
        #pragma unroll
        for (int pc = 0; pc < 8; ++pc)
            vf[pc] = *(const bf16x8*)(Vb + cbase + (size_t)(pc*64 + c16*4 + g)*8);

        // S^T = K_chunk * Q^T  -> lane holds S[n=c16][m = 16s + 4g + r]
        f32x4 st[2];
        #pragma unroll
        for (int s = 0; s < 2; ++s) {
            f32x4 a = (f32x4){0.f,0.f,0.f,0.f};
            #pragma unroll
            for (int ks = 0; ks < 4; ++ks)
                a = __builtin_amdgcn_mfma_f32_16x16x32_bf16(kf[s][ks], qf[ks], a, 0, 0, 0);
            st[s] = a;
        }

        // prefetch next chunk's K into the now-free kf regs (hidden under softmax+PV)
        const size_t nbase = (size_t)((it + 1) & 31) * 4096;
        #pragma unroll
        for (int s = 0; s < 2; ++s)
            #pragma unroll
            for (int ks = 0; ks < 4; ++ks)
                kf[s][ks] = *(const bf16x8*)(Kb + nbase + (size_t)((s*4 + ks)*64 + lane)*8);

        float cmax = -1e30f;
        #pragma unroll
        for (int s = 0; s < 2; ++s)
            #pragma unroll
            for (int r = 0; r < 4; ++r) { st[s][r] *= scale; cmax = fmaxf(cmax, st[s][r]); }
        cmax = fmaxf(cmax, __shfl_xor(cmax, 16));
        cmax = fmaxf(cmax, __shfl_xor(cmax, 32));
        const float mnew  = fmaxf(mi, cmax);
        const float alpha = __expf(mi - mnew);

        float psum = 0.f;
        uint2 pw[2];
        #pragma unroll
        for (int s = 0; s < 2; ++s) {
            float p0 = __expf(st[s][0] - mnew), p1 = __expf(st[s][1] - mnew);
            float p2 = __expf(st[s][2] - mnew), p3 = __expf(st[s][3] - mnew);
            psum += (p0 + p1) + (p2 + p3);
            pw[s].x = (unsigned int)f2b(p0) | ((unsigned int)f2b(p1) << 16);
            pw[s].y = (unsigned int)f2b(p2) | ((unsigned int)f2b(p3) << 16);
        }
        psum += __shfl_xor(psum, 16);
        psum += __shfl_xor(psum, 32);
        li = li * alpha + psum;
        mi = mnew;

        // write P (row c16, cols m-local 16s+4g..+3) into padded scratch
        unsigned short* pbase = &pls[wave][it & 1][0];
        *(uint2*)(pbase + c16*40 + 0*16 + g*4) = pw[0];
        *(uint2*)(pbase + c16*40 + 1*16 + g*4) = pw[1];

        // rescale o accumulator (rows n = 4g + r; stats live at lane index n)
        float ar[4];
        #pragma unroll
        for (int r = 0; r < 4; ++r) ar[r] = __shfl(alpha, g*4 + r);
        #pragma unroll
        for (int pc = 0; pc < 8; ++pc)
            #pragma unroll
            for (int r = 0; r < 4; ++r) oacc[pc][r] *= ar[r];

        // per-wave LDS scratch: in-wave ds_write->ds_read ordering handled by compiler
        bf16x8 pa = *(const bf16x8*)(pbase + c16*40 + g*8);
        #pragma unroll
        for (int pc = 0; pc < 8; ++pc)
            oacc[pc] = __builtin_amdgcn_mfma_f32_16x16x32_bf16(pa, vf[pc], oacc[pc], 0, 0, 0);
    }

    float lr[4];
    #pragma unroll
    for (int r = 0; r < 4; ++r) lr[r] = 1.f / __shfl(li, g*4 + r);
    #pragma unroll
    for (int pc = 0; pc < 8; ++pc)
        #pragma unroll
        for (int r = 0; r < 4; ++r) {
            const int n = n0 + g*4 + r;
            obuf[((size_t)bb*SEQ + n)*INNER + hh*DIM + pc*16 + c16] = f2b(oacc[pc][r] * lr[r]);
        }
}

// ---------------- launch ----------------
extern "C" void kernel_launch(void* const* d_in, const int* in_sizes, int n_in,
                              void* d_out, int out_size, void* d_ws, size_t ws_size,
                              hipStream_t stream)
{
    const float* x         = (const float*)d_in[0];
    const float* y         = (const float*)d_in[1];
    const float* norm_x_w  = (const float*)d_in[2];
    const float* norm_x_b  = (const float*)d_in[3];
    const float* norm_y_w  = (const float*)d_in[4];
    const float* norm_y_b  = (const float*)d_in[5];
    const float* q_w       = (const float*)d_in[6];
    const float* kv_w      = (const float*)d_in[7];
    const float* proj_w    = (const float*)d_in[8];
    const float* proj_b    = (const float*)d_in[9];
    const float* ls1_gamma = (const float*)d_in[10];
    const float* norm_o_w  = (const float*)d_in[11];
    const float* norm_o_b  = (const float*)d_in[12];
    const float* fc1_w     = (const float*)d_in[13];
    const float* fc1_b     = (const float*)d_in[14];
    const float* fc2_w     = (const float*)d_in[15];
    const float* fc2_b     = (const float*)d_in[16];
    const float* ls2_gamma = (const float*)d_in[17];

    char* ws = (char*)d_ws;
    size_t off = 0;
    auto alloc = [&](size_t bytes) {
        void* p = ws + off;
        off += (bytes + 255) & ~(size_t)255;
        return p;
    };
    unsigned short* xn  = (unsigned short*)alloc((size_t)ROWS*DIM*2);
    unsigned short* yn  = (unsigned short*)alloc((size_t)ROWS*DIM*2);
    unsigned short* qb  = (unsigned short*)alloc((size_t)ROWS*INNER*2);
    unsigned short* kpm = (unsigned short*)alloc((size_t)ROWS*INNER*2);
    unsigned short* vpm = (unsigned short*)alloc((size_t)ROWS*INNER*2);
    unsigned short* ob  = (unsigned short*)alloc((size_t)ROWS*INNER*2);
    float*          x1  = (float*)alloc((size_t)ROWS*DIM*4);
    unsigned short* hin = (unsigned short*)alloc((size_t)ROWS*DIM*2);
    unsigned short* h1  = (unsigned short*)alloc((size_t)ROWS*HIDDEN*2);
    unsigned short* wq   = (unsigned short*)alloc((size_t)INNER*DIM*2);
    unsigned short* wkv  = (unsigned short*)alloc((size_t)2*INNER*DIM*2);
    unsigned short* wpr  = (unsigned short*)alloc((size_t)DIM*INNER*2);
    unsigned short* wf1  = (unsigned short*)alloc((size_t)HIDDEN*DIM*2);
    unsigned short* wf2  = (unsigned short*)alloc((size_t)DIM*HIDDEN*2);

    // 0) convert all weights f32 -> bf16 (one launch)
    cvt_all_kernel<<<dim3(640), 256, 0, stream>>>(
        q_w, wq, kv_w, wkv, proj_w, wpr, fc1_w, wf1, fc2_w, wf2);

    // 1) LayerNorms of x and y (one launch)
    ln_dual_kernel<<<dim3(ROWS/4, 2), 256, 0, stream>>>(
        x, norm_x_w, norm_x_b, xn, y, norm_y_w, norm_y_b, yn);

    // 2) q / kv projections (kv epilogue writes attention-permuted K and V)
    gemm_kernel<128, 0><<<dim3(INNER/64, ROWS/64), 256, 0, stream>>>(
        xn, wq, qb, nullptr, nullptr, nullptr, nullptr);
    gemm_kernel<128, 1><<<dim3(2*INNER/64, ROWS/64), 256, 0, stream>>>(
        yn, wkv, kpm, vpm, nullptr, nullptr, nullptr);

    // 3) attention
    attn_kernel<<<dim3(BATCH*HEADS*16), 256, 0, stream>>>(qb, kpm, vpm, ob);

    // 4) proj + bias + ls1*resid(x,f32) -> x1 (f32)
    gemm_kernel<1024, 2><<<dim3(DIM/64, ROWS/64), 256, 0, stream>>>(
        ob, wpr, x1, nullptr, proj_b, ls1_gamma, x);

    // 5) LN(x1) -> hin (bf16)
    ln_kernel<<<dim3(ROWS/4), 256, 0, stream>>>(x1, norm_o_w, norm_o_b, hin);

    // 6) fc1 + relu -> h1 (bf16)
    gemm_kernel<128, 3><<<dim3(HIDDEN/64, ROWS/64), 256, 0, stream>>>(
        hin, wf1, h1, nullptr, fc1_b, nullptr, nullptr);

    // 7) fc2 + bias + ls2*resid(x1,f32) -> d_out (f32)
    gemm_kernel<512, 4><<<dim3(DIM/64, ROWS/64), 256, 0, stream>>>(
        h1, wf2, d_out, nullptr, fc2_b, ls2_gamma, x1);
}

// Round 7
// 235.726 us; speedup vs baseline: 1.6297x; 1.0546x over previous
//
#include <hip/hip_runtime.h>
#include <stdint.h>

#define DIM    128
#define HEADS  8
#define INNER  1024
#define HIDDEN 512
#define BATCH  8
#define SEQ    1024
#define ROWS   8192   // BATCH*SEQ

typedef __attribute__((ext_vector_type(8))) short bf16x8;
typedef __attribute__((ext_vector_type(4))) float f32x4;
typedef __attribute__((ext_vector_type(4))) unsigned short u16x4;

// q is pre-scaled by 1/sqrt(128) * log2(e) so attention works in exp2 domain
#define QSCALE (0.08838834764831845f * 1.4426950408889634f)

static __device__ __forceinline__ float b2f(unsigned short u) {
    union { float f; unsigned int i; } v; v.i = ((unsigned int)u) << 16; return v.f;
}
static __device__ __forceinline__ unsigned short f2b(float f) {
    union { float f; unsigned int i; } v; v.f = f;
    unsigned int x = v.i;
    return (unsigned short)((x + 0x7fffu + ((x >> 16) & 1u)) >> 16);
}
static __device__ __forceinline__ unsigned int cvt_pk_bf16(float a, float b) {
    unsigned int r;
    asm("v_cvt_pk_bf16_f32 %0, %1, %2" : "=v"(r) : "v"(a), "v"(b));
    return r;
}

// ---------------- all weight conversions f32 -> bf16 in one launch ----------------
__global__ __launch_bounds__(256)
void cvt_all_kernel(const float* __restrict__ s0, unsigned short* __restrict__ d0,
                    const float* __restrict__ s1, unsigned short* __restrict__ d1,
                    const float* __restrict__ s2, unsigned short* __restrict__ d2,
                    const float* __restrict__ s3, unsigned short* __restrict__ d3,
                    const float* __restrict__ s4, unsigned short* __restrict__ d4)
{
    int j = blockIdx.x * 256 + threadIdx.x;
    const float* s; unsigned short* d;
    if (j < 32768)                 { s = s0; d = d0; }
    else if ((j -= 32768) < 65536) { s = s1; d = d1; }
    else if ((j -= 65536) < 32768) { s = s2; d = d2; }
    else if ((j -= 32768) < 16384) { s = s3; d = d3; }
    else { j -= 16384;               s = s4; d = d4; }
    const float4 v = ((const float4*)s)[j];
    u16x4 o;
    o[0] = f2b(v.x); o[1] = f2b(v.y); o[2] = f2b(v.z); o[3] = f2b(v.w);
    ((u16x4*)d)[j] = o;
}

// ---------------- LayerNorm core ----------------
static __device__ __forceinline__ void ln_row(const float* __restrict__ in,
                                              const float* __restrict__ w,
                                              const float* __restrict__ b,
                                              unsigned short* __restrict__ out,
                                              int row, int lane)
{
    const float2 xv = *(const float2*)(in + (size_t)row*DIM + lane*2);
    float x0 = xv.x, x1 = xv.y;
    float s = x0 + x1;
    float q = x0*x0 + x1*x1;
    #pragma unroll
    for (int off = 32; off > 0; off >>= 1) {
        s += __shfl_xor(s, off);
        q += __shfl_xor(q, off);
    }
    const float mu  = s * (1.0f/128.0f);
    const float var = q * (1.0f/128.0f) - mu*mu;
    const float rs  = rsqrtf(var + 1e-5f);
    const float2 wv = *(const float2*)(w + lane*2);
    const float2 bv = *(const float2*)(b + lane*2);
    unsigned short o0 = f2b((x0 - mu) * rs * wv.x + bv.x);
    unsigned short o1 = f2b((x1 - mu) * rs * wv.y + bv.y);
    *(unsigned int*)(out + (size_t)row*DIM + lane*2) = (unsigned int)o0 | ((unsigned int)o1 << 16);
}

__global__ __launch_bounds__(256)
void ln_kernel(const float* __restrict__ in,
               const float* __restrict__ w,
               const float* __restrict__ b,
               unsigned short* __restrict__ out)
{
    const int wave = threadIdx.x >> 6;
    const int lane = threadIdx.x & 63;
    ln_row(in, w, b, out, blockIdx.x * 4 + wave, lane);
}

__global__ __launch_bounds__(256)
void ln_dual_kernel(const float* __restrict__ inx, const float* __restrict__ wx,
                    const float* __restrict__ bx, unsigned short* __restrict__ outx,
                    const float* __restrict__ iny, const float* __restrict__ wy,
                    const float* __restrict__ by, unsigned short* __restrict__ outy)
{
    const int wave = threadIdx.x >> 6;
    const int lane = threadIdx.x & 63;
    const int row  = blockIdx.x * 4 + wave;
    if (blockIdx.y == 0) ln_row(inx, wx, bx, outx, row, lane);
    else                 ln_row(iny, wy, by, outy, row, lane);
}

// ---------------- Generic TN GEMM: C(MxN) = A(MxK) * W(NxK)^T ----------------
// EPI: 0=q scatter (pre-scaled), 1=kv scatter into attention-permuted K/V layouts,
//      2=proj(+bias,*ls1,+x -> f32), 3=fc1(+bias,relu -> bf16), 4=fc2(+bias,*ls2,+x1 -> f32 out)
template<int K, int EPI>
__global__ __launch_bounds__(256)
void gemm_kernel(const unsigned short* __restrict__ A,
                 const unsigned short* __restrict__ W,
                 void* __restrict__ out0, void* __restrict__ out1,
                 const float* __restrict__ bias,
                 const float* __restrict__ gamma,
                 const float* __restrict__ resid)
{
    const int lane = threadIdx.x & 63;
    const int wave = threadIdx.x >> 6;
    const int g    = lane >> 4;
    const int c16  = lane & 15;
    const int mb   = blockIdx.y * 64 + wave * 16;
    const int nb   = blockIdx.x * 64;

    f32x4 acc[4];
    #pragma unroll
    for (int t = 0; t < 4; ++t) acc[t] = (f32x4){0.f, 0.f, 0.f, 0.f};

    const unsigned short* arow = A + (size_t)(mb + c16) * K;
    #pragma unroll 4
    for (int ks = 0; ks < K/32; ++ks) {
        const int koff = ks*32 + g*8;
        bf16x8 af = *(const bf16x8*)(arow + koff);
        #pragma unroll
        for (int t = 0; t < 4; ++t) {
            bf16x8 wf = *(const bf16x8*)(W + (size_t)(nb + t*16 + c16) * K + koff);
            acc[t] = __builtin_amdgcn_mfma_f32_16x16x32_bf16(af, wf, acc[t], 0, 0, 0);
        }
    }

    #pragma unroll
    for (int t = 0; t < 4; ++t) {
        #pragma unroll
        for (int r = 0; r < 4; ++r) {
            const int row = mb + g*4 + r;
            const int col = nb + t*16 + c16;
            const float v = acc[t][r];
            if (EPI == 0) {
                const int bb = row >> 10, n = row & 1023, hh = col >> 7, p = col & 127;
                ((unsigned short*)out0)[(((size_t)(bb*HEADS + hh))*SEQ + n)*DIM + p] = f2b(v * QSCALE);
            } else if (EPI == 1) {
                const int bb = row >> 10, m = row & 1023;
                const int chunk = m >> 5;
                if (col < INNER) {
                    // K permuted: [chunk][s:2][ks:4][g:4][c16:16][e:8]
                    const int hh = col >> 7, p = col & 127;
                    const int sl = (m >> 4) & 1, cl = m & 15;
                    const int ksl = p >> 5, gl = (p >> 3) & 3, el = p & 7;
                    ((unsigned short*)out0)[(size_t)(bb*HEADS + hh)*SEQ*DIM
                        + (size_t)((chunk*8 + sl*4 + ksl)*64 + gl*16 + cl)*8 + el] = f2b(v);
                } else {
                    // V permuted: [chunk][pc:8][c16:16][g:4][e:8]
                    const int c2 = col - INNER;
                    const int hh = c2 >> 7, p = c2 & 127;
                    const int gl = (m >> 3) & 3, el = m & 7;
                    const int pcl = p >> 4, cl = p & 15;
                    ((unsigned short*)out1)[(size_t)(bb*HEADS + hh)*SEQ*DIM
                        + (size_t)((chunk*8 + pcl)*64 + cl*4 + gl)*8 + el] = f2b(v);
                }
            } else if (EPI == 2) {
                const float xv = resid[(size_t)row*DIM + col];
                ((float*)out0)[(size_t)row*DIM + col] = xv + (v + bias[col]) * gamma[col];
            } else if (EPI == 3) {
                const float hv = v + bias[col];
                ((unsigned short*)out0)[(size_t)row*HIDDEN + col] = f2b(fmaxf(hv, 0.f));
            } else {
                const float ov = resid[(size_t)row*DIM + col] + (v + bias[col]) * gamma[col];
                ((float*)out0)[(size_t)row*DIM + col] = ov;
            }
        }
    }
}

// ---------------- Flash attention, software-pipelined ----------------
// q pre-scaled to exp2 domain; K/V pre-permuted for coalesced 1KB wave loads.
__global__ __launch_bounds__(256)
void attn_kernel(const unsigned short* __restrict__ qbuf,  // (B,H,N,P) pre-scaled
                 const unsigned short* __restrict__ kperm, // per bh: [chunk][s][ks][lane][8]
                 const unsigned short* __restrict__ vperm, // per bh: [chunk][pc][c16][g][8]
                 unsigned short* __restrict__ obuf)        // (B,N,INNER)
{
    __shared__ unsigned short pls[4][2][16*40];

    const int lane = threadIdx.x & 63;
    const int wave = threadIdx.x >> 6;
    const int g    = lane >> 4;
    const int c16  = lane & 15;
    const int bh   = blockIdx.x >> 4;
    const int nblk = blockIdx.x & 15;
    const int n0   = nblk * 64 + wave * 16;
    const int bb   = bh >> 3, hh = bh & 7;

    const unsigned short* Q  = qbuf  + (size_t)bh * SEQ * DIM;
    const unsigned short* Kb = kperm + (size_t)bh * SEQ * DIM;
    const unsigned short* Vb = vperm + (size_t)bh * SEQ * DIM;

    bf16x8 qf[4];
    #pragma unroll
    for (int ks = 0; ks < 4; ++ks)
        qf[ks] = *(const bf16x8*)(Q + (size_t)(n0 + c16)*DIM + ks*32 + g*8);

    f32x4 oacc[8];
    #pragma unroll
    for (int pc = 0; pc < 8; ++pc) oacc[pc] = (f32x4){0.f,0.f,0.f,0.f};
    float mi = -1e30f, li = 0.f;

    // prologue: K(0), V(0); st = QK(0); then issue K(1)
    bf16x8 kf[2][4], vf[8];
    #pragma unroll
    for (int s = 0; s < 2; ++s)
        #pragma unroll
        for (int ks = 0; ks < 4; ++ks)
            kf[s][ks] = *(const bf16x8*)(Kb + (size_t)((s*4 + ks)*64 + lane)*8);
    #pragma unroll
    for (int pc = 0; pc < 8; ++pc)
        vf[pc] = *(const bf16x8*)(Vb + (size_t)(pc*64 + c16*4 + g)*8);

    f32x4 st[2];
    #pragma unroll
    for (int s = 0; s < 2; ++s) {
        f32x4 a = (f32x4){0.f,0.f,0.f,0.f};
        #pragma unroll
        for (int ks = 0; ks < 4; ++ks)
            a = __builtin_amdgcn_mfma_f32_16x16x32_bf16(kf[s][ks], qf[ks], a, 0, 0, 0);
        st[s] = a;
    }
    #pragma unroll
    for (int s = 0; s < 2; ++s)
        #pragma unroll
        for (int ks = 0; ks < 4; ++ks)
            kf[s][ks] = *(const bf16x8*)(Kb + 4096 + (size_t)((s*4 + ks)*64 + lane)*8);
    __builtin_amdgcn_sched_barrier(0);

    for (int it = 0; it < 32; ++it) {
        // ---- softmax on st (scores for chunk it, already in log2 domain) ----
        float cmax = -1e30f;
        #pragma unroll
        for (int s = 0; s < 2; ++s)
            #pragma unroll
            for (int r = 0; r < 4; ++r) cmax = fmaxf(cmax, st[s][r]);
        cmax = fmaxf(cmax, __shfl_xor(cmax, 16));
        cmax = fmaxf(cmax, __shfl_xor(cmax, 32));

        if (!__all(cmax - mi <= 8.0f)) {   // rare rescale path
            const float mnew  = fmaxf(mi, cmax);
            const float alpha = exp2f(mi - mnew);
            mi = mnew;
            li *= alpha;
            float ar[4];
            #pragma unroll
            for (int r = 0; r < 4; ++r) ar[r] = __shfl(alpha, g*4 + r);
            #pragma unroll
            for (int pc = 0; pc < 8; ++pc)
                #pragma unroll
                for (int r = 0; r < 4; ++r) oacc[pc][r] *= ar[r];
        }

        float psum = 0.f;
        uint2 pw[2];
        #pragma unroll
        for (int s = 0; s < 2; ++s) {
            float p0 = exp2f(st[s][0] - mi), p1 = exp2f(st[s][1] - mi);
            float p2 = exp2f(st[s][2] - mi), p3 = exp2f(st[s][3] - mi);
            psum += (p0 + p1) + (p2 + p3);
            pw[s].x = cvt_pk_bf16(p0, p1);
            pw[s].y = cvt_pk_bf16(p2, p3);
        }
        psum += __shfl_xor(psum, 16);
        psum += __shfl_xor(psum, 32);
        li += psum;

        unsigned short* pbase = &pls[wave][it & 1][0];
        *(uint2*)(pbase + c16*40 + 0*16 + g*4) = pw[0];
        *(uint2*)(pbase + c16*40 + 1*16 + g*4) = pw[1];
        bf16x8 pa = *(const bf16x8*)(pbase + c16*40 + g*8);

        // ---- QK for chunk it+1 (kf holds K(it+1)); fills MFMA pipe under softmax ----
        #pragma unroll
        for (int s = 0; s < 2; ++s) {
            f32x4 a = (f32x4){0.f,0.f,0.f,0.f};
            #pragma unroll
            for (int ks = 0; ks < 4; ++ks)
                a = __builtin_amdgcn_mfma_f32_16x16x32_bf16(kf[s][ks], qf[ks], a, 0, 0, 0);
            st[s] = a;
        }
        // reload kf with K(it+2) — pinned here, consumed next iter
        {
            const size_t kbase = (size_t)((it + 2) & 31) * 4096;
            #pragma unroll
            for (int s = 0; s < 2; ++s)
                #pragma unroll
                for (int ks = 0; ks < 4; ++ks)
                    kf[s][ks] = *(const bf16x8*)(Kb + kbase + (size_t)((s*4 + ks)*64 + lane)*8);
        }
        __builtin_amdgcn_sched_barrier(0);

        // ---- PV for chunk it ----
        #pragma unroll
        for (int pc = 0; pc < 8; ++pc)
            oacc[pc] = __builtin_amdgcn_mfma_f32_16x16x32_bf16(pa, vf[pc], oacc[pc], 0, 0, 0);

        // reload vf with V(it+1) — pinned here, consumed next iter
        {
            const size_t vbase = (size_t)((it + 1) & 31) * 4096;
            #pragma unroll
            for (int pc = 0; pc < 8; ++pc)
                vf[pc] = *(const bf16x8*)(Vb + vbase + (size_t)(pc*64 + c16*4 + g)*8);
        }
        __builtin_amdgcn_sched_barrier(0);
    }

    float lr[4];
    #pragma unroll
    for (int r = 0; r < 4; ++r) lr[r] = 1.f / __shfl(li, g*4 + r);
    #pragma unroll
    for (int pc = 0; pc < 8; ++pc)
        #pragma unroll
        for (int r = 0; r < 4; ++r) {
            const int n = n0 + g*4 + r;
            obuf[((size_t)bb*SEQ + n)*INNER + hh*DIM + pc*16 + c16] = f2b(oacc[pc][r] * lr[r]);
        }
}

// ---------------- launch ----------------
extern "C" void kernel_launch(void* const* d_in, const int* in_sizes, int n_in,
                              void* d_out, int out_size, void* d_ws, size_t ws_size,
                              hipStream_t stream)
{
    const float* x         = (const float*)d_in[0];
    const float* y         = (const float*)d_in[1];
    const float* norm_x_w  = (const float*)d_in[2];
    const float* norm_x_b  = (const float*)d_in[3];
    const float* norm_y_w  = (const float*)d_in[4];
    const float* norm_y_b  = (const float*)d_in[5];
    const float* q_w       = (const float*)d_in[6];
    const float* kv_w      = (const float*)d_in[7];
    const float* proj_w    = (const float*)d_in[8];
    const float* proj_b    = (const float*)d_in[9];
    const float* ls1_gamma = (const float*)d_in[10];
    const float* norm_o_w  = (const float*)d_in[11];
    const float* norm_o_b  = (const float*)d_in[12];
    const float* fc1_w     = (const float*)d_in[13];
    const float* fc1_b     = (const float*)d_in[14];
    const float* fc2_w     = (const float*)d_in[15];
    const float* fc2_b     = (const float*)d_in[16];
    const float* ls2_gamma = (const float*)d_in[17];

    char* ws = (char*)d_ws;
    size_t off = 0;
    auto alloc = [&](size_t bytes) {
        void* p = ws + off;
        off += (bytes + 255) & ~(size_t)255;
        return p;
    };
    unsigned short* xn  = (unsigned short*)alloc((size_t)ROWS*DIM*2);
    unsigned short* yn  = (unsigned short*)alloc((size_t)ROWS*DIM*2);
    unsigned short* qb  = (unsigned short*)alloc((size_t)ROWS*INNER*2);
    unsigned short* kpm = (unsigned short*)alloc((size_t)ROWS*INNER*2);
    unsigned short* vpm = (unsigned short*)alloc((size_t)ROWS*INNER*2);
    unsigned short* ob  = (unsigned short*)alloc((size_t)ROWS*INNER*2);
    float*          x1  = (float*)alloc((size_t)ROWS*DIM*4);
    unsigned short* hin = (unsigned short*)alloc((size_t)ROWS*DIM*2);
    unsigned short* h1  = (unsigned short*)alloc((size_t)ROWS*HIDDEN*2);
    unsigned short* wq   = (unsigned short*)alloc((size_t)INNER*DIM*2);
    unsigned short* wkv  = (unsigned short*)alloc((size_t)2*INNER*DIM*2);
    unsigned short* wpr  = (unsigned short*)alloc((size_t)DIM*INNER*2);
    unsigned short* wf1  = (unsigned short*)alloc((size_t)HIDDEN*DIM*2);
    unsigned short* wf2  = (unsigned short*)alloc((size_t)DIM*HIDDEN*2);

    // 0) convert all weights f32 -> bf16 (one launch)
    cvt_all_kernel<<<dim3(640), 256, 0, stream>>>(
        q_w, wq, kv_w, wkv, proj_w, wpr, fc1_w, wf1, fc2_w, wf2);

    // 1) LayerNorms of x and y (one launch)
    ln_dual_kernel<<<dim3(ROWS/4, 2), 256, 0, stream>>>(
        x, norm_x_w, norm_x_b, xn, y, norm_y_w, norm_y_b, yn);

    // 2) q / kv projections (kv epilogue writes attention-permuted K and V)
    gemm_kernel<128, 0><<<dim3(INNER/64, ROWS/64), 256, 0, stream>>>(
        xn, wq, qb, nullptr, nullptr, nullptr, nullptr);
    gemm_kernel<128, 1><<<dim3(2*INNER/64, ROWS/64), 256, 0, stream>>>(
        yn, wkv, kpm, vpm, nullptr, nullptr, nullptr);

    // 3) attention
    attn_kernel<<<dim3(BATCH*HEADS*16), 256, 0, stream>>>(qb, kpm, vpm, ob);

    // 4) proj + bias + ls1*resid(x,f32) -> x1 (f32)
    gemm_kernel<1024, 2><<<dim3(DIM/64, ROWS/64), 256, 0, stream>>>(
        ob, wpr, x1, nullptr, proj_b, ls1_gamma, x);

    // 5) LN(x1) -> hin (bf16)
    ln_kernel<<<dim3(ROWS/4), 256, 0, stream>>>(x1, norm_o_w, norm_o_b, hin);

    // 6) fc1 + relu -> h1 (bf16)
    gemm_kernel<128, 3><<<dim3(HIDDEN/64, ROWS/64), 256, 0, stream>>>(
        hin, wf1, h1, nullptr, fc1_b, nullptr, nullptr);

    // 7) fc2 + bias + ls2*resid(x1,f32) -> d_out (f32)
    gemm_kernel<512, 4><<<dim3(DIM/64, ROWS/64), 256, 0, stream>>>(
        h1, wf2, d_out, nullptr, fc2_b, ls2_gamma, x1);
}

// Round 8
// 192.062 us; speedup vs baseline: 2.0003x; 1.2273x over previous
//
#include <hip/hip_runtime.h>
#include <stdint.h>

#define DIM    128
#define HEADS  8
#define INNER  1024
#define HIDDEN 512
#define BATCH  8
#define SEQ    1024
#define ROWS   8192   // BATCH*SEQ

typedef __attribute__((ext_vector_type(8))) short bf16x8;
typedef __attribute__((ext_vector_type(4))) float f32x4;
typedef __attribute__((ext_vector_type(4))) unsigned short u16x4;

// q is pre-scaled by 1/sqrt(128) * log2(e) so attention works in exp2 domain
#define QSCALE (0.08838834764831845f * 1.4426950408889634f)

static __device__ __forceinline__ float b2f(unsigned short u) {
    union { float f; unsigned int i; } v; v.i = ((unsigned int)u) << 16; return v.f;
}
static __device__ __forceinline__ unsigned short f2b(float f) {
    union { float f; unsigned int i; } v; v.f = f;
    unsigned int x = v.i;
    return (unsigned short)((x + 0x7fffu + ((x >> 16) & 1u)) >> 16);
}
static __device__ __forceinline__ unsigned int cvt_pk_bf16(float a, float b) {
    unsigned int r;
    asm("v_cvt_pk_bf16_f32 %0, %1, %2" : "=v"(r) : "v"(a), "v"(b));
    return r;
}

// MFMA A-fragment ("PA") layout: lane-linear 1KB blocks per (row-tile, k-chunk).
// flat(row,k) = ((row>>4)*(K/32) + (k>>5))*512 + (((k>>3)&3)*16 + (row&15))*8 + (k&7)
static __device__ __forceinline__ size_t pa_idx(int row, int k, int K) {
    return ((size_t)((row >> 4) * (K >> 5) + (k >> 5)) << 9)
         + (size_t)(((((k >> 3) & 3) << 4) + (row & 15)) << 3) + (size_t)(k & 7);
}

// ---------------- weight f32 -> bf16 + permute to PA layout ----------------
template<int K>
static __device__ __forceinline__ void cvtw(const float* __restrict__ W,
                                            unsigned short* __restrict__ Wp, int j)
{
    const int c  = j & 15;
    const int gw = (j >> 4) & 3;
    const int blk = j >> 6;
    const int ks = blk & ((K >> 5) - 1);
    const int nt = blk / (K >> 5);
    const int n  = nt * 16 + c;
    const int kb = ks * 32 + gw * 8;
    const float4 a = *(const float4*)(W + (size_t)n * K + kb);
    const float4 b = *(const float4*)(W + (size_t)n * K + kb + 4);
    u16x4 o0, o1;
    o0[0] = f2b(a.x); o0[1] = f2b(a.y); o0[2] = f2b(a.z); o0[3] = f2b(a.w);
    o1[0] = f2b(b.x); o1[1] = f2b(b.y); o1[2] = f2b(b.z); o1[3] = f2b(b.w);
    *(u16x4*)(Wp + (size_t)j * 8)     = o0;
    *(u16x4*)(Wp + (size_t)j * 8 + 4) = o1;
}

// segments (threads = N*K/8): q 16384 | kv 32768 | proj 16384 | fc1 8192 | fc2 8192
__global__ __launch_bounds__(256)
void cvt_all_kernel(const float* __restrict__ s0, unsigned short* __restrict__ d0,
                    const float* __restrict__ s1, unsigned short* __restrict__ d1,
                    const float* __restrict__ s2, unsigned short* __restrict__ d2,
                    const float* __restrict__ s3, unsigned short* __restrict__ d3,
                    const float* __restrict__ s4, unsigned short* __restrict__ d4)
{
    int j = blockIdx.x * 256 + threadIdx.x;
    if (j < 16384)                 { cvtw<128>(s0, d0, j);  return; }
    if ((j -= 16384) < 32768)      { cvtw<128>(s1, d1, j);  return; }
    if ((j -= 32768) < 16384)      { cvtw<1024>(s2, d2, j); return; }
    if ((j -= 16384) < 8192)       { cvtw<128>(s3, d3, j);  return; }
    j -= 8192;                       cvtw<512>(s4, d4, j);
}

// ---------------- LayerNorm core: f32 row-major in, bf16 PA(128) out ----------------
static __device__ __forceinline__ void ln_row(const float* __restrict__ in,
                                              const float* __restrict__ w,
                                              const float* __restrict__ b,
                                              unsigned short* __restrict__ out,
                                              int row, int lane)
{
    const float2 xv = *(const float2*)(in + (size_t)row*DIM + lane*2);
    float x0 = xv.x, x1 = xv.y;
    float s = x0 + x1;
    float q = x0*x0 + x1*x1;
    #pragma unroll
    for (int off = 32; off > 0; off >>= 1) {
        s += __shfl_xor(s, off);
        q += __shfl_xor(q, off);
    }
    const float mu  = s * (1.0f/128.0f);
    const float var = q * (1.0f/128.0f) - mu*mu;
    const float rs  = rsqrtf(var + 1e-5f);
    const float2 wv = *(const float2*)(w + lane*2);
    const float2 bv = *(const float2*)(b + lane*2);
    unsigned short o0 = f2b((x0 - mu) * rs * wv.x + bv.x);
    unsigned short o1 = f2b((x1 - mu) * rs * wv.y + bv.y);
    *(unsigned int*)(out + pa_idx(row, lane*2, 128)) = (unsigned int)o0 | ((unsigned int)o1 << 16);
}

__global__ __launch_bounds__(256)
void ln_kernel(const float* __restrict__ in,
               const float* __restrict__ w,
               const float* __restrict__ b,
               unsigned short* __restrict__ out)
{
    ln_row(in, w, b, out, blockIdx.x * 4 + (threadIdx.x >> 6), threadIdx.x & 63);
}

__global__ __launch_bounds__(256)
void ln_dual_kernel(const float* __restrict__ inx, const float* __restrict__ wx,
                    const float* __restrict__ bx, unsigned short* __restrict__ outx,
                    const float* __restrict__ iny, const float* __restrict__ wy,
                    const float* __restrict__ by, unsigned short* __restrict__ outy)
{
    const int row  = blockIdx.x * 4 + (threadIdx.x >> 6);
    const int lane = threadIdx.x & 63;
    if (blockIdx.y == 0) ln_row(inx, wx, bx, outx, row, lane);
    else                 ln_row(iny, wy, by, outy, row, lane);
}

// ---------------- Generic TN GEMM on PA-layout A and W ----------------
// C(MxN) = A(MxK) * W(NxK)^T ; block = 4 waves stacked in M; wave tile 16(M) x 64(N)
// EPI: 0=q scatter (pre-scaled), 1=kv scatter into attention-permuted K/V layouts,
//      2=proj(+bias,*ls1,+x -> f32), 3=fc1(+bias,relu -> PA bf16), 4=fc2(+bias,*ls2,+x1 -> f32 out)
template<int K, int EPI>
__global__ __launch_bounds__(256)
void gemm_kernel(const unsigned short* __restrict__ A,   // PA(K)
                 const unsigned short* __restrict__ W,   // PA(K) (N rows)
                 void* __restrict__ out0, void* __restrict__ out1,
                 const float* __restrict__ bias,
                 const float* __restrict__ gamma,
                 const float* __restrict__ resid)
{
    const int lane = threadIdx.x & 63;
    const int wave = threadIdx.x >> 6;
    const int g    = lane >> 4;
    const int c16  = lane & 15;
    const int mb   = blockIdx.y * 64 + wave * 16;
    const int nb   = blockIdx.x * 64;
    const int mt   = blockIdx.y * 4 + wave;
    const int nt0  = blockIdx.x * 4;

    f32x4 acc[4];
    #pragma unroll
    for (int t = 0; t < 4; ++t) acc[t] = (f32x4){0.f, 0.f, 0.f, 0.f};

    #pragma unroll 4
    for (int ks = 0; ks < K/32; ++ks) {
        bf16x8 af = *(const bf16x8*)(A + (((size_t)(mt*(K>>5) + ks)) << 9) + lane*8);
        #pragma unroll
        for (int t = 0; t < 4; ++t) {
            bf16x8 wf = *(const bf16x8*)(W + (((size_t)((nt0 + t)*(K>>5) + ks)) << 9) + lane*8);
            acc[t] = __builtin_amdgcn_mfma_f32_16x16x32_bf16(af, wf, acc[t], 0, 0, 0);
        }
    }

    #pragma unroll
    for (int t = 0; t < 4; ++t) {
        #pragma unroll
        for (int r = 0; r < 4; ++r) {
            const int row = mb + g*4 + r;
            const int col = nb + t*16 + c16;
            const float v = acc[t][r];
            if (EPI == 0) {
                const int bb = row >> 10, n = row & 1023, hh = col >> 7, p = col & 127;
                ((unsigned short*)out0)[(((size_t)(bb*HEADS + hh))*SEQ + n)*DIM + p] = f2b(v * QSCALE);
            } else if (EPI == 1) {
                const int bb = row >> 10, m = row & 1023;
                const int chunk = m >> 5;
                if (col < INNER) {
                    // K permuted: [chunk][s:2][ks:4][g:4][c16:16][e:8]
                    const int hh = col >> 7, p = col & 127;
                    const int sl = (m >> 4) & 1, cl = m & 15;
                    const int ksl = p >> 5, gl = (p >> 3) & 3, el = p & 7;
                    ((unsigned short*)out0)[(size_t)(bb*HEADS + hh)*SEQ*DIM
                        + (size_t)((chunk*8 + sl*4 + ksl)*64 + gl*16 + cl)*8 + el] = f2b(v);
                } else {
                    // V permuted: [chunk][pc:8][c16:16][g:4][e:8]
                    const int c2 = col - INNER;
                    const int hh = c2 >> 7, p = c2 & 127;
                    const int gl = (m >> 3) & 3, el = m & 7;
                    const int pcl = p >> 4, cl = p & 15;
                    ((unsigned short*)out1)[(size_t)(bb*HEADS + hh)*SEQ*DIM
                        + (size_t)((chunk*8 + pcl)*64 + cl*4 + gl)*8 + el] = f2b(v);
                }
            } else if (EPI == 2) {
                const float xv = resid[(size_t)row*DIM + col];
                ((float*)out0)[(size_t)row*DIM + col] = xv + (v + bias[col]) * gamma[col];
            } else if (EPI == 3) {
                const float hv = v + bias[col];
                ((unsigned short*)out0)[pa_idx(row, col, HIDDEN)] = f2b(fmaxf(hv, 0.f));
            } else {
                const float ov = resid[(size_t)row*DIM + col] + (v + bias[col]) * gamma[col];
                ((float*)out0)[(size_t)row*DIM + col] = ov;
            }
        }
    }
}

// ---------------- Flash attention v3: shuffle-free common path ----------------
// q pre-scaled to exp2 domain; K/V pre-permuted; output written in PA(1024) for proj.
__global__ __launch_bounds__(256)
void attn_kernel(const unsigned short* __restrict__ qbuf,  // (B,H,N,P) pre-scaled
                 const unsigned short* __restrict__ kperm, // per bh: [chunk][s][ks][lane][8]
                 const unsigned short* __restrict__ vperm, // per bh: [chunk][pc][c16][g][8]
                 unsigned short* __restrict__ obuf)        // PA(1024) over rows (B*SEQ)
{
    __shared__ unsigned short pls[4][2][16*40];

    const int lane = threadIdx.x & 63;
    const int wave = threadIdx.x >> 6;
    const int g    = lane >> 4;
    const int c16  = lane & 15;
    const int bh   = blockIdx.x >> 4;
    const int nblk = blockIdx.x & 15;
    const int n0   = nblk * 64 + wave * 16;
    const int bb   = bh >> 3, hh = bh & 7;

    const unsigned short* Q  = qbuf  + (size_t)bh * SEQ * DIM;
    const unsigned short* Kb = kperm + (size_t)bh * SEQ * DIM;
    const unsigned short* Vb = vperm + (size_t)bh * SEQ * DIM;

    bf16x8 qf[4];
    #pragma unroll
    for (int ks = 0; ks < 4; ++ks)
        qf[ks] = *(const bf16x8*)(Q + (size_t)(n0 + c16)*DIM + ks*32 + g*8);

    f32x4 oacc[8];
    #pragma unroll
    for (int pc = 0; pc < 8; ++pc) oacc[pc] = (f32x4){0.f,0.f,0.f,0.f};
    float mi = 8.0f;              // row-uniform initial max guess (exp2 domain); offset cancels in 1/li
    float li0 = 0.f, li1 = 0.f;   // per-lane partial sums, reduced across g after the loop

    // prologue: K(0), V(0); st = QK(0); issue K(1)
    bf16x8 kf[2][4], vf[8];
    #pragma unroll
    for (int s = 0; s < 2; ++s)
        #pragma unroll
        for (int ks = 0; ks < 4; ++ks)
            kf[s][ks] = *(const bf16x8*)(Kb + (s*4 + ks)*512 + lane*8);
    #pragma unroll
    for (int pc = 0; pc < 8; ++pc)
        vf[pc] = *(const bf16x8*)(Vb + pc*512 + (c16*4 + g)*8);

    f32x4 st[2];
    #pragma unroll
    for (int s = 0; s < 2; ++s) {
        f32x4 a = (f32x4){0.f,0.f,0.f,0.f};
        #pragma unroll
        for (int ks = 0; ks < 4; ++ks)
            a = __builtin_amdgcn_mfma_f32_16x16x32_bf16(kf[s][ks], qf[ks], a, 0, 0, 0);
        st[s] = a;
    }
    #pragma unroll
    for (int s = 0; s < 2; ++s)
        #pragma unroll
        for (int ks = 0; ks < 4; ++ks)
            kf[s][ks] = *(const bf16x8*)(Kb + 4096 + (s*4 + ks)*512 + lane*8);
    __builtin_amdgcn_sched_barrier(0);

    // linear prefetch pointers (buffers padded; overrun loads never consumed)
    const unsigned short* kpref = Kb + 2*4096 + lane*8;
    const unsigned short* vpref = Vb + 1*4096 + (c16*4 + g)*8;

    for (int it = 0; it < 32; ++it) {
        // ---- softmax on st (chunk it): no cross-lane ops in the common path ----
        float cmax = st[0][0];
        cmax = fmaxf(cmax, st[0][1]); cmax = fmaxf(cmax, st[0][2]); cmax = fmaxf(cmax, st[0][3]);
        cmax = fmaxf(cmax, st[1][0]); cmax = fmaxf(cmax, st[1][1]);
        cmax = fmaxf(cmax, st[1][2]); cmax = fmaxf(cmax, st[1][3]);

        if (!__all(cmax - mi <= 8.0f)) {     // rare: true row-max rescale
            float rmax = cmax;
            rmax = fmaxf(rmax, __shfl_xor(rmax, 16));
            rmax = fmaxf(rmax, __shfl_xor(rmax, 32));
            const float mnew  = fmaxf(mi, rmax);
            const float alpha = exp2f(mi - mnew);
            mi = mnew;
            li0 *= alpha; li1 *= alpha;
            float ar[4];
            #pragma unroll
            for (int r = 0; r < 4; ++r) ar[r] = __shfl(alpha, g*4 + r);
            #pragma unroll
            for (int pc = 0; pc < 8; ++pc)
                #pragma unroll
                for (int r = 0; r < 4; ++r) oacc[pc][r] *= ar[r];
        }

        uint2 pw[2];
        {
            float p0 = exp2f(st[0][0] - mi), p1 = exp2f(st[0][1] - mi);
            float p2 = exp2f(st[0][2] - mi), p3 = exp2f(st[0][3] - mi);
            float p4 = exp2f(st[1][0] - mi), p5 = exp2f(st[1][1] - mi);
            float p6 = exp2f(st[1][2] - mi), p7 = exp2f(st[1][3] - mi);
            li0 += (p0 + p1) + (p2 + p3);
            li1 += (p4 + p5) + (p6 + p7);
            pw[0].x = cvt_pk_bf16(p0, p1); pw[0].y = cvt_pk_bf16(p2, p3);
            pw[1].x = cvt_pk_bf16(p4, p5); pw[1].y = cvt_pk_bf16(p6, p7);
        }

        unsigned short* pbase = &pls[wave][it & 1][0];
        *(uint2*)(pbase + c16*40 + 0*16 + g*4) = pw[0];
        *(uint2*)(pbase + c16*40 + 1*16 + g*4) = pw[1];

        // ---- QK for chunk it+1 (hides the LDS write->read round-trip) ----
        #pragma unroll
        for (int s = 0; s < 2; ++s) {
            f32x4 a = (f32x4){0.f,0.f,0.f,0.f};
            #pragma unroll
            for (int ks = 0; ks < 4; ++ks)
                a = __builtin_amdgcn_mfma_f32_16x16x32_bf16(kf[s][ks], qf[ks], a, 0, 0, 0);
            st[s] = a;
        }
        // prefetch K(it+2): linear pointer walk
        #pragma unroll
        for (int s = 0; s < 2; ++s)
            #pragma unroll
            for (int ks = 0; ks < 4; ++ks)
                kf[s][ks] = *(const bf16x8*)(kpref + (s*4 + ks)*512);
        kpref += 4096;
        __builtin_amdgcn_sched_barrier(0);

        // ---- PV for chunk it ----
        bf16x8 pa = *(const bf16x8*)(pbase + c16*40 + g*8);
        #pragma unroll
        for (int pc = 0; pc < 8; ++pc)
            oacc[pc] = __builtin_amdgcn_mfma_f32_16x16x32_bf16(pa, vf[pc], oacc[pc], 0, 0, 0);

        // prefetch V(it+1)
        #pragma unroll
        for (int pc = 0; pc < 8; ++pc)
            vf[pc] = *(const bf16x8*)(vpref + pc*512);
        vpref += 4096;
        __builtin_amdgcn_sched_barrier(0);
    }

    float li = li0 + li1;
    li += __shfl_xor(li, 16);
    li += __shfl_xor(li, 32);
    float lr[4];
    #pragma unroll
    for (int r = 0; r < 4; ++r) lr[r] = 1.f / __shfl(li, g*4 + r);
    #pragma unroll
    for (int pc = 0; pc < 8; ++pc)
        #pragma unroll
        for (int r = 0; r < 4; ++r) {
            const int row = bb*SEQ + n0 + g*4 + r;
            const int k   = hh*DIM + pc*16 + c16;
            obuf[pa_idx(row, k, INNER)] = f2b(oacc[pc][r] * lr[r]);
        }
}

// ---------------- launch ----------------
extern "C" void kernel_launch(void* const* d_in, const int* in_sizes, int n_in,
                              void* d_out, int out_size, void* d_ws, size_t ws_size,
                              hipStream_t stream)
{
    const float* x         = (const float*)d_in[0];
    const float* y         = (const float*)d_in[1];
    const float* norm_x_w  = (const float*)d_in[2];
    const float* norm_x_b  = (const float*)d_in[3];
    const float* norm_y_w  = (const float*)d_in[4];
    const float* norm_y_b  = (const float*)d_in[5];
    const float* q_w       = (const float*)d_in[6];
    const float* kv_w      = (const float*)d_in[7];
    const float* proj_w    = (const float*)d_in[8];
    const float* proj_b    = (const float*)d_in[9];
    const float* ls1_gamma = (const float*)d_in[10];
    const float* norm_o_w  = (const float*)d_in[11];
    const float* norm_o_b  = (const float*)d_in[12];
    const float* fc1_w     = (const float*)d_in[13];
    const float* fc1_b     = (const float*)d_in[14];
    const float* fc2_w     = (const float*)d_in[15];
    const float* fc2_b     = (const float*)d_in[16];
    const float* ls2_gamma = (const float*)d_in[17];

    char* ws = (char*)d_ws;
    size_t off = 0;
    auto alloc = [&](size_t bytes) {
        void* p = ws + off;
        off += (bytes + 255) & ~(size_t)255;
        return p;
    };
    unsigned short* xn  = (unsigned short*)alloc((size_t)ROWS*DIM*2);
    unsigned short* yn  = (unsigned short*)alloc((size_t)ROWS*DIM*2);
    unsigned short* qb  = (unsigned short*)alloc((size_t)ROWS*INNER*2);
    unsigned short* kpm = (unsigned short*)alloc((size_t)ROWS*INNER*2 + 32768); // +16KB prefetch pad
    unsigned short* vpm = (unsigned short*)alloc((size_t)ROWS*INNER*2 + 32768);
    unsigned short* ob  = (unsigned short*)alloc((size_t)ROWS*INNER*2);
    float*          x1  = (float*)alloc((size_t)ROWS*DIM*4);
    unsigned short* hin = (unsigned short*)alloc((size_t)ROWS*DIM*2);
    unsigned short* h1  = (unsigned short*)alloc((size_t)ROWS*HIDDEN*2);
    unsigned short* wq   = (unsigned short*)alloc((size_t)INNER*DIM*2);
    unsigned short* wkv  = (unsigned short*)alloc((size_t)2*INNER*DIM*2);
    unsigned short* wpr  = (unsigned short*)alloc((size_t)DIM*INNER*2);
    unsigned short* wf1  = (unsigned short*)alloc((size_t)HIDDEN*DIM*2);
    unsigned short* wf2  = (unsigned short*)alloc((size_t)DIM*HIDDEN*2);

    // 0) convert + permute all weights (one launch; 81920 threads)
    cvt_all_kernel<<<dim3(320), 256, 0, stream>>>(
        q_w, wq, kv_w, wkv, proj_w, wpr, fc1_w, wf1, fc2_w, wf2);

    // 1) LayerNorms of x and y -> PA(128)
    ln_dual_kernel<<<dim3(ROWS/4, 2), 256, 0, stream>>>(
        x, norm_x_w, norm_x_b, xn, y, norm_y_w, norm_y_b, yn);

    // 2) q / kv projections (kv epilogue writes attention-permuted K and V)
    gemm_kernel<128, 0><<<dim3(INNER/64, ROWS/64), 256, 0, stream>>>(
        xn, wq, qb, nullptr, nullptr, nullptr, nullptr);
    gemm_kernel<128, 1><<<dim3(2*INNER/64, ROWS/64), 256, 0, stream>>>(
        yn, wkv, kpm, vpm, nullptr, nullptr, nullptr);

    // 3) attention -> ob in PA(1024)
    attn_kernel<<<dim3(BATCH*HEADS*16), 256, 0, stream>>>(qb, kpm, vpm, ob);

    // 4) proj + bias + ls1*resid(x,f32) -> x1 (f32 row-major)
    gemm_kernel<1024, 2><<<dim3(DIM/64, ROWS/64), 256, 0, stream>>>(
        ob, wpr, x1, nullptr, proj_b, ls1_gamma, x);

    // 5) LN(x1) -> hin PA(128)
    ln_kernel<<<dim3(ROWS/4), 256, 0, stream>>>(x1, norm_o_w, norm_o_b, hin);

    // 6) fc1 + relu -> h1 PA(512)
    gemm_kernel<128, 3><<<dim3(HIDDEN/64, ROWS/64), 256, 0, stream>>>(
        hin, wf1, h1, nullptr, fc1_b, nullptr, nullptr);

    // 7) fc2 + bias + ls2*resid(x1,f32) -> d_out (f32)
    gemm_kernel<512, 4><<<dim3(DIM/64, ROWS/64), 256, 0, stream>>>(
        h1, wf2, d_out, nullptr, fc2_b, ls2_gamma, x1);
}

// Round 9
// 137.645 us; speedup vs baseline: 2.7911x; 1.3953x over previous
//
#include <hip/hip_runtime.h>
#include <stdint.h>

#define DIM    128
#define HEADS  8
#define INNER  1024
#define HIDDEN 512
#define BATCH  8
#define SEQ    1024
#define ROWS   8192   // BATCH*SEQ

typedef __attribute__((ext_vector_type(8))) short bf16x8;
typedef __attribute__((ext_vector_type(4))) float f32x4;
typedef __attribute__((ext_vector_type(4))) unsigned short u16x4;

// q is pre-scaled by 1/sqrt(128) * log2(e) so attention works in exp2 domain
#define QSCALE (0.08838834764831845f * 1.4426950408889634f)

#define AS1 __attribute__((address_space(1)))
#define AS3 __attribute__((address_space(3)))

static __device__ __forceinline__ float b2f(unsigned short u) {
    union { float f; unsigned int i; } v; v.i = ((unsigned int)u) << 16; return v.f;
}
static __device__ __forceinline__ unsigned short f2b(float f) {
    union { float f; unsigned int i; } v; v.f = f;
    unsigned int x = v.i;
    return (unsigned short)((x + 0x7fffu + ((x >> 16) & 1u)) >> 16);
}
static __device__ __forceinline__ unsigned int cvt_pk_bf16(float a, float b) {
    unsigned int r;
    asm("v_cvt_pk_bf16_f32 %0, %1, %2" : "=v"(r) : "v"(a), "v"(b));
    return r;
}
// async global->LDS, 16B per lane; LDS dest is wave-uniform base + lane*16
static __device__ __forceinline__ void gl_lds16(const unsigned short* g, unsigned short* l) {
    __builtin_amdgcn_global_load_lds((AS1 void*)g, (AS3 void*)l, 16, 0, 0);
}

// MFMA A-fragment ("PA") layout: lane-linear 1KB blocks per (row-tile, k-chunk).
static __device__ __forceinline__ size_t pa_idx(int row, int k, int K) {
    return ((size_t)((row >> 4) * (K >> 5) + (k >> 5)) << 9)
         + (size_t)(((((k >> 3) & 3) << 4) + (row & 15)) << 3) + (size_t)(k & 7);
}

// ---------------- weight f32 -> bf16 + permute to PA layout ----------------
template<int K>
static __device__ __forceinline__ void cvtw(const float* __restrict__ W,
                                            unsigned short* __restrict__ Wp, int j)
{
    const int c  = j & 15;
    const int gw = (j >> 4) & 3;
    const int blk = j >> 6;
    const int ks = blk & ((K >> 5) - 1);
    const int nt = blk / (K >> 5);
    const int n  = nt * 16 + c;
    const int kb = ks * 32 + gw * 8;
    const float4 a = *(const float4*)(W + (size_t)n * K + kb);
    const float4 b = *(const float4*)(W + (size_t)n * K + kb + 4);
    u16x4 o0, o1;
    o0[0] = f2b(a.x); o0[1] = f2b(a.y); o0[2] = f2b(a.z); o0[3] = f2b(a.w);
    o1[0] = f2b(b.x); o1[1] = f2b(b.y); o1[2] = f2b(b.z); o1[3] = f2b(b.w);
    *(u16x4*)(Wp + (size_t)j * 8)     = o0;
    *(u16x4*)(Wp + (size_t)j * 8 + 4) = o1;
}

__global__ __launch_bounds__(256)
void cvt_all_kernel(const float* __restrict__ s0, unsigned short* __restrict__ d0,
                    const float* __restrict__ s1, unsigned short* __restrict__ d1,
                    const float* __restrict__ s2, unsigned short* __restrict__ d2,
                    const float* __restrict__ s3, unsigned short* __restrict__ d3,
                    const float* __restrict__ s4, unsigned short* __restrict__ d4)
{
    int j = blockIdx.x * 256 + threadIdx.x;
    if (j < 16384)                 { cvtw<128>(s0, d0, j);  return; }
    if ((j -= 16384) < 32768)      { cvtw<128>(s1, d1, j);  return; }
    if ((j -= 32768) < 16384)      { cvtw<1024>(s2, d2, j); return; }
    if ((j -= 16384) < 8192)       { cvtw<128>(s3, d3, j);  return; }
    j -= 8192;                       cvtw<512>(s4, d4, j);
}

// ---------------- LayerNorm core: f32 row-major in, bf16 PA(128) out ----------------
static __device__ __forceinline__ void ln_row(const float* __restrict__ in,
                                              const float* __restrict__ w,
                                              const float* __restrict__ b,
                                              unsigned short* __restrict__ out,
                                              int row, int lane)
{
    const float2 xv = *(const float2*)(in + (size_t)row*DIM + lane*2);
    float x0 = xv.x, x1 = xv.y;
    float s = x0 + x1;
    float q = x0*x0 + x1*x1;
    #pragma unroll
    for (int off = 32; off > 0; off >>= 1) {
        s += __shfl_xor(s, off);
        q += __shfl_xor(q, off);
    }
    const float mu  = s * (1.0f/128.0f);
    const float var = q * (1.0f/128.0f) - mu*mu;
    const float rs  = rsqrtf(var + 1e-5f);
    const float2 wv = *(const float2*)(w + lane*2);
    const float2 bv = *(const float2*)(b + lane*2);
    unsigned short o0 = f2b((x0 - mu) * rs * wv.x + bv.x);
    unsigned short o1 = f2b((x1 - mu) * rs * wv.y + bv.y);
    *(unsigned int*)(out + pa_idx(row, lane*2, 128)) = (unsigned int)o0 | ((unsigned int)o1 << 16);
}

__global__ __launch_bounds__(256)
void ln_kernel(const float* __restrict__ in,
               const float* __restrict__ w,
               const float* __restrict__ b,
               unsigned short* __restrict__ out)
{
    ln_row(in, w, b, out, blockIdx.x * 4 + (threadIdx.x >> 6), threadIdx.x & 63);
}

__global__ __launch_bounds__(256)
void ln_dual_kernel(const float* __restrict__ inx, const float* __restrict__ wx,
                    const float* __restrict__ bx, unsigned short* __restrict__ outx,
                    const float* __restrict__ iny, const float* __restrict__ wy,
                    const float* __restrict__ by, unsigned short* __restrict__ outy)
{
    const int row  = blockIdx.x * 4 + (threadIdx.x >> 6);
    const int lane = threadIdx.x & 63;
    if (blockIdx.y == 0) ln_row(inx, wx, bx, outx, row, lane);
    else                 ln_row(iny, wy, by, outy, row, lane);
}

// ---------------- Generic TN GEMM on PA-layout A and W ----------------
template<int K, int EPI>
__global__ __launch_bounds__(256)
void gemm_kernel(const unsigned short* __restrict__ A,   // PA(K)
                 const unsigned short* __restrict__ W,   // PA(K) (N rows)
                 void* __restrict__ out0, void* __restrict__ out1,
                 const float* __restrict__ bias,
                 const float* __restrict__ gamma,
                 const float* __restrict__ resid)
{
    const int lane = threadIdx.x & 63;
    const int wave = threadIdx.x >> 6;
    const int g    = lane >> 4;
    const int c16  = lane & 15;
    const int mb   = blockIdx.y * 64 + wave * 16;
    const int nb   = blockIdx.x * 64;
    const int mt   = blockIdx.y * 4 + wave;
    const int nt0  = blockIdx.x * 4;

    f32x4 acc[4];
    #pragma unroll
    for (int t = 0; t < 4; ++t) acc[t] = (f32x4){0.f, 0.f, 0.f, 0.f};

    #pragma unroll 4
    for (int ks = 0; ks < K/32; ++ks) {
        bf16x8 af = *(const bf16x8*)(A + (((size_t)(mt*(K>>5) + ks)) << 9) + lane*8);
        #pragma unroll
        for (int t = 0; t < 4; ++t) {
            bf16x8 wf = *(const bf16x8*)(W + (((size_t)((nt0 + t)*(K>>5) + ks)) << 9) + lane*8);
            acc[t] = __builtin_amdgcn_mfma_f32_16x16x32_bf16(af, wf, acc[t], 0, 0, 0);
        }
    }

    #pragma unroll
    for (int t = 0; t < 4; ++t) {
        #pragma unroll
        for (int r = 0; r < 4; ++r) {
            const int row = mb + g*4 + r;
            const int col = nb + t*16 + c16;
            const float v = acc[t][r];
            if (EPI == 0) {
                const int bb = row >> 10, n = row & 1023, hh = col >> 7, p = col & 127;
                ((unsigned short*)out0)[(((size_t)(bb*HEADS + hh))*SEQ + n)*DIM + p] = f2b(v * QSCALE);
            } else if (EPI == 1) {
                const int bb = row >> 10, m = row & 1023;
                const int chunk = m >> 5;
                if (col < INNER) {
                    // K permuted: [chunk][s:2][ks:4][g:4][c16:16][e:8]  (lane-linear)
                    const int hh = col >> 7, p = col & 127;
                    const int sl = (m >> 4) & 1, cl = m & 15;
                    const int ksl = p >> 5, gl = (p >> 3) & 3, el = p & 7;
                    ((unsigned short*)out0)[(size_t)(bb*HEADS + hh)*SEQ*DIM
                        + (size_t)((chunk*8 + sl*4 + ksl)*64 + gl*16 + cl)*8 + el] = f2b(v);
                } else {
                    // V permuted: [chunk][pc:8][g:4][c16:16][e:8]  (lane-linear)
                    const int c2 = col - INNER;
                    const int hh = c2 >> 7, p = c2 & 127;
                    const int gl = (m >> 3) & 3, el = m & 7;
                    const int pcl = p >> 4, cl = p & 15;
                    ((unsigned short*)out1)[(size_t)(bb*HEADS + hh)*SEQ*DIM
                        + (size_t)((chunk*8 + pcl)*64 + gl*16 + cl)*8 + el] = f2b(v);
                }
            } else if (EPI == 2) {
                const float xv = resid[(size_t)row*DIM + col];
                ((float*)out0)[(size_t)row*DIM + col] = xv + (v + bias[col]) * gamma[col];
            } else if (EPI == 3) {
                const float hv = v + bias[col];
                ((unsigned short*)out0)[pa_idx(row, col, HIDDEN)] = f2b(fmaxf(hv, 0.f));
            } else {
                const float ov = resid[(size_t)row*DIM + col] + (v + bias[col]) * gamma[col];
                ((float*)out0)[(size_t)row*DIM + col] = ov;
            }
        }
    }
}

// ---------------- Flash attention v4: LDS-staged K/V shared by 4 waves ----------------
// 4 waves x 32 q-rows = 128 q-rows per block; 8 blocks per bh (same XCD via swizzle).
// K/V chunk (8KB+8KB) staged once per block via global_load_lds, double-buffered.
__global__ __launch_bounds__(256)
void attn_kernel(const unsigned short* __restrict__ qbuf,  // (B,H,N,P) pre-scaled
                 const unsigned short* __restrict__ kperm, // per bh: [chunk][frag 4096]
                 const unsigned short* __restrict__ vperm, // per bh: [chunk][frag 4096]
                 unsigned short* __restrict__ obuf)        // PA(1024) over rows (B*SEQ)
{
    __shared__ unsigned short kbuf[2][4096];   // 8KB per chunk
    __shared__ unsigned short vbuf[2][4096];
    __shared__ unsigned short pls[4][2][640];  // per (wave, ng): 16 rows x 40

    const int lane = threadIdx.x & 63;
    const int wave = threadIdx.x >> 6;
    const int g    = lane >> 4;
    const int c16  = lane & 15;

    // XCD swizzle: all 8 q-blocks of one bh land on the same XCD (j%8)
    const int j    = blockIdx.x;
    const int bh   = (j & 7) * 8 + (j >> 6);
    const int nblk = (j >> 3) & 7;
    const int n0   = nblk * 128 + wave * 32;
    const int bb   = bh >> 3, hh = bh & 7;

    const unsigned short* Q  = qbuf  + (size_t)bh * SEQ * DIM;
    const unsigned short* Kb = kperm + (size_t)bh * SEQ * DIM;
    const unsigned short* Vb = vperm + (size_t)bh * SEQ * DIM;

    // stage chunk 0 (each wave covers segments 2w, 2w+1 of K and V)
    const int seg0 = wave * 2;
    #pragma unroll
    for (int s2 = 0; s2 < 2; ++s2) {
        gl_lds16(Kb + (seg0 + s2)*512 + lane*8, &kbuf[0][(seg0 + s2)*512]);
        gl_lds16(Vb + (seg0 + s2)*512 + lane*8, &vbuf[0][(seg0 + s2)*512]);
    }

    // Q fragments: 32 rows = 2 groups of 16
    bf16x8 qf[2][4];
    #pragma unroll
    for (int ng = 0; ng < 2; ++ng)
        #pragma unroll
        for (int ks = 0; ks < 4; ++ks)
            qf[ng][ks] = *(const bf16x8*)(Q + (size_t)(n0 + ng*16 + c16)*DIM + ks*32 + g*8);

    f32x4 oacc[2][8];
    #pragma unroll
    for (int ng = 0; ng < 2; ++ng)
        #pragma unroll
        for (int pc = 0; pc < 8; ++pc) oacc[ng][pc] = (f32x4){0.f,0.f,0.f,0.f};
    float mi[2]  = {8.0f, 8.0f};     // row-uniform initial max guess (exp2 domain)
    float li0[2] = {0.f, 0.f};
    float li1[2] = {0.f, 0.f};

    __syncthreads();   // chunk 0 staged (implicit vmcnt(0) before barrier)

    int cur = 0;
    for (int it = 0; it < 32; ++it, cur ^= 1) {
        // ---- stage chunk it+1 into the other buffer (async, drains at barrier) ----
        if (it != 31) {
            const unsigned short* Ks = Kb + (size_t)(it + 1) * 4096;
            const unsigned short* Vs = Vb + (size_t)(it + 1) * 4096;
            #pragma unroll
            for (int s2 = 0; s2 < 2; ++s2) {
                gl_lds16(Ks + (seg0 + s2)*512 + lane*8, &kbuf[cur ^ 1][(seg0 + s2)*512]);
                gl_lds16(Vs + (seg0 + s2)*512 + lane*8, &vbuf[cur ^ 1][(seg0 + s2)*512]);
            }
        }

        // ---- K fragments from LDS + QK^T (both q-groups share kf) ----
        bf16x8 kf[2][4];
        #pragma unroll
        for (int s = 0; s < 2; ++s)
            #pragma unroll
            for (int ks = 0; ks < 4; ++ks)
                kf[s][ks] = *(const bf16x8*)&kbuf[cur][(s*4 + ks)*512 + lane*8];

        f32x4 st[2][2];
        #pragma unroll
        for (int ng = 0; ng < 2; ++ng)
            #pragma unroll
            for (int s = 0; s < 2; ++s) {
                f32x4 a = (f32x4){0.f,0.f,0.f,0.f};
                #pragma unroll
                for (int ks = 0; ks < 4; ++ks)
                    a = __builtin_amdgcn_mfma_f32_16x16x32_bf16(kf[s][ks], qf[ng][ks], a, 0, 0, 0);
                st[ng][s] = a;
            }

        // ---- V fragments from LDS (issued early; consumed after softmax) ----
        bf16x8 vf[8];
        #pragma unroll
        for (int pc = 0; pc < 8; ++pc)
            vf[pc] = *(const bf16x8*)&vbuf[cur][(pc*64 + lane)*8];

        // ---- softmax (per-lane common path; rescale branch ~never taken) ----
        float cmax[2];
        #pragma unroll
        for (int ng = 0; ng < 2; ++ng) {
            float c = st[ng][0][0];
            c = fmaxf(c, st[ng][0][1]); c = fmaxf(c, st[ng][0][2]); c = fmaxf(c, st[ng][0][3]);
            c = fmaxf(c, st[ng][1][0]); c = fmaxf(c, st[ng][1][1]);
            c = fmaxf(c, st[ng][1][2]); c = fmaxf(c, st[ng][1][3]);
            cmax[ng] = c;
        }
        const int ok = (cmax[0] - mi[0] <= 8.0f) && (cmax[1] - mi[1] <= 8.0f);
        if (!__all(ok)) {
            #pragma unroll
            for (int ng = 0; ng < 2; ++ng) {
                float rmax = cmax[ng];
                rmax = fmaxf(rmax, __shfl_xor(rmax, 16));
                rmax = fmaxf(rmax, __shfl_xor(rmax, 32));
                const float mnew  = fmaxf(mi[ng], rmax);
                const float alpha = exp2f(mi[ng] - mnew);
                mi[ng] = mnew;
                li0[ng] *= alpha; li1[ng] *= alpha;
                float ar[4];
                #pragma unroll
                for (int r = 0; r < 4; ++r) ar[r] = __shfl(alpha, g*4 + r);
                #pragma unroll
                for (int pc = 0; pc < 8; ++pc)
                    #pragma unroll
                    for (int r = 0; r < 4; ++r) oacc[ng][pc][r] *= ar[r];
            }
        }

        #pragma unroll
        for (int ng = 0; ng < 2; ++ng) {
            float p0 = exp2f(st[ng][0][0] - mi[ng]), p1 = exp2f(st[ng][0][1] - mi[ng]);
            float p2 = exp2f(st[ng][0][2] - mi[ng]), p3 = exp2f(st[ng][0][3] - mi[ng]);
            float p4 = exp2f(st[ng][1][0] - mi[ng]), p5 = exp2f(st[ng][1][1] - mi[ng]);
            float p6 = exp2f(st[ng][1][2] - mi[ng]), p7 = exp2f(st[ng][1][3] - mi[ng]);
            li0[ng] += (p0 + p1) + (p2 + p3);
            li1[ng] += (p4 + p5) + (p6 + p7);
            uint2 w0, w1;
            w0.x = cvt_pk_bf16(p0, p1); w0.y = cvt_pk_bf16(p2, p3);
            w1.x = cvt_pk_bf16(p4, p5); w1.y = cvt_pk_bf16(p6, p7);
            unsigned short* pb = &pls[wave][ng][0];
            *(uint2*)(pb + c16*40 + 0*16 + g*4) = w0;
            *(uint2*)(pb + c16*40 + 1*16 + g*4) = w1;
        }

        // ---- PV ----
        #pragma unroll
        for (int ng = 0; ng < 2; ++ng) {
            bf16x8 pa = *(const bf16x8*)(&pls[wave][ng][0] + c16*40 + g*8);
            #pragma unroll
            for (int pc = 0; pc < 8; ++pc)
                oacc[ng][pc] = __builtin_amdgcn_mfma_f32_16x16x32_bf16(pa, vf[pc], oacc[ng][pc], 0, 0, 0);
        }

        __syncthreads();   // stage(it+1) drained + all waves done with buf[cur]
    }

    // ---- epilogue: normalize and write PA(1024) ----
    #pragma unroll
    for (int ng = 0; ng < 2; ++ng) {
        float li = li0[ng] + li1[ng];
        li += __shfl_xor(li, 16);
        li += __shfl_xor(li, 32);
        float lr[4];
        #pragma unroll
        for (int r = 0; r < 4; ++r) lr[r] = 1.f / __shfl(li, g*4 + r);
        #pragma unroll
        for (int pc = 0; pc < 8; ++pc)
            #pragma unroll
            for (int r = 0; r < 4; ++r) {
                const int row = bb*SEQ + n0 + ng*16 + g*4 + r;
                const int k   = hh*DIM + pc*16 + c16;
                obuf[pa_idx(row, k, INNER)] = f2b(oacc[ng][pc][r] * lr[r]);
            }
    }
}

// ---------------- launch ----------------
extern "C" void kernel_launch(void* const* d_in, const int* in_sizes, int n_in,
                              void* d_out, int out_size, void* d_ws, size_t ws_size,
                              hipStream_t stream)
{
    const float* x         = (const float*)d_in[0];
    const float* y         = (const float*)d_in[1];
    const float* norm_x_w  = (const float*)d_in[2];
    const float* norm_x_b  = (const float*)d_in[3];
    const float* norm_y_w  = (const float*)d_in[4];
    const float* norm_y_b  = (const float*)d_in[5];
    const float* q_w       = (const float*)d_in[6];
    const float* kv_w      = (const float*)d_in[7];
    const float* proj_w    = (const float*)d_in[8];
    const float* proj_b    = (const float*)d_in[9];
    const float* ls1_gamma = (const float*)d_in[10];
    const float* norm_o_w  = (const float*)d_in[11];
    const float* norm_o_b  = (const float*)d_in[12];
    const float* fc1_w     = (const float*)d_in[13];
    const float* fc1_b     = (const float*)d_in[14];
    const float* fc2_w     = (const float*)d_in[15];
    const float* fc2_b     = (const float*)d_in[16];
    const float* ls2_gamma = (const float*)d_in[17];

    char* ws = (char*)d_ws;
    size_t off = 0;
    auto alloc = [&](size_t bytes) {
        void* p = ws + off;
        off += (bytes + 255) & ~(size_t)255;
        return p;
    };
    unsigned short* xn  = (unsigned short*)alloc((size_t)ROWS*DIM*2);
    unsigned short* yn  = (unsigned short*)alloc((size_t)ROWS*DIM*2);
    unsigned short* qb  = (unsigned short*)alloc((size_t)ROWS*INNER*2);
    unsigned short* kpm = (unsigned short*)alloc((size_t)ROWS*INNER*2 + 32768);
    unsigned short* vpm = (unsigned short*)alloc((size_t)ROWS*INNER*2 + 32768);
    unsigned short* ob  = (unsigned short*)alloc((size_t)ROWS*INNER*2);
    float*          x1  = (float*)alloc((size_t)ROWS*DIM*4);
    unsigned short* hin = (unsigned short*)alloc((size_t)ROWS*DIM*2);
    unsigned short* h1  = (unsigned short*)alloc((size_t)ROWS*HIDDEN*2);
    unsigned short* wq   = (unsigned short*)alloc((size_t)INNER*DIM*2);
    unsigned short* wkv  = (unsigned short*)alloc((size_t)2*INNER*DIM*2);
    unsigned short* wpr  = (unsigned short*)alloc((size_t)DIM*INNER*2);
    unsigned short* wf1  = (unsigned short*)alloc((size_t)HIDDEN*DIM*2);
    unsigned short* wf2  = (unsigned short*)alloc((size_t)DIM*HIDDEN*2);

    // 0) convert + permute all weights (one launch)
    cvt_all_kernel<<<dim3(320), 256, 0, stream>>>(
        q_w, wq, kv_w, wkv, proj_w, wpr, fc1_w, wf1, fc2_w, wf2);

    // 1) LayerNorms of x and y -> PA(128)
    ln_dual_kernel<<<dim3(ROWS/4, 2), 256, 0, stream>>>(
        x, norm_x_w, norm_x_b, xn, y, norm_y_w, norm_y_b, yn);

    // 2) q / kv projections (kv epilogue writes attention-permuted K and V)
    gemm_kernel<128, 0><<<dim3(INNER/64, ROWS/64), 256, 0, stream>>>(
        xn, wq, qb, nullptr, nullptr, nullptr, nullptr);
    gemm_kernel<128, 1><<<dim3(2*INNER/64, ROWS/64), 256, 0, stream>>>(
        yn, wkv, kpm, vpm, nullptr, nullptr, nullptr);

    // 3) attention -> ob in PA(1024); 512 blocks, XCD-swizzled
    attn_kernel<<<dim3(512), 256, 0, stream>>>(qb, kpm, vpm, ob);

    // 4) proj + bias + ls1*resid(x,f32) -> x1 (f32 row-major)
    gemm_kernel<1024, 2><<<dim3(DIM/64, ROWS/64), 256, 0, stream>>>(
        ob, wpr, x1, nullptr, proj_b, ls1_gamma, x);

    // 5) LN(x1) -> hin PA(128)
    ln_kernel<<<dim3(ROWS/4), 256, 0, stream>>>(x1, norm_o_w, norm_o_b, hin);

    // 6) fc1 + relu -> h1 PA(512)
    gemm_kernel<128, 3><<<dim3(HIDDEN/64, ROWS/64), 256, 0, stream>>>(
        hin, wf1, h1, nullptr, fc1_b, nullptr, nullptr);

    // 7) fc2 + bias + ls2*resid(x1,f32) -> d_out (f32)
    gemm_kernel<512, 4><<<dim3(DIM/64, ROWS/64), 256, 0, stream>>>(
        h1, wf2, d_out, nullptr, fc2_b, ls2_gamma, x1);
}